// Round 12
// baseline (610.215 us; speedup 1.0000x reference)
//
#include <hip/hip_runtime.h>
#include <cstdint>
#include <math.h>
#include <type_traits>

typedef __bf16 bf16_t;
typedef __bf16 bf16x8 __attribute__((ext_vector_type(8)));
typedef float f32x4 __attribute__((ext_vector_type(4)));
typedef uint32_t u32x4 __attribute__((ext_vector_type(4)));
typedef uint32_t u32x2 __attribute__((ext_vector_type(2)));

#define DI __device__ __forceinline__

DI float bflo(uint32_t u){ return __builtin_bit_cast(float, (uint32_t)(u << 16)); }
DI float bfhi(uint32_t u){ return __builtin_bit_cast(float, (uint32_t)(u & 0xffff0000u)); }
DI uint16_t f2bf(float f){ bf16_t h = (bf16_t)f; return __builtin_bit_cast(uint16_t, h); }
DI uint32_t pk2(float a, float b){ return (uint32_t)f2bf(a) | ((uint32_t)f2bf(b) << 16); }
// gelu(tanh-approx) == x * sigmoid(2u): HW exp+rcp instead of libm tanhf.
DI float geluf(float x){
  float t = x * x;
  float p = fmaf(t, 0.0356774081f, 0.7978845608f);
  float e = __expf(-2.0f * x * p);
  return x * __builtin_amdgcn_rcpf(1.0f + e);
}

#if defined(__has_builtin)
#if __has_builtin(__builtin_amdgcn_global_load_lds)
#define USE_GLLDS 1
#endif
#endif

#if USE_GLLDS
DI void gload_lds16(const void* g, void* l){
  __builtin_amdgcn_global_load_lds((__attribute__((address_space(1))) void*)g,
                                   (__attribute__((address_space(3))) void*)l, 16, 0, 0);
}
#endif

// ---------------- zero V^T pad rows (rows 72..79 of each [80][256] slab) ----------------
__global__ __launch_bounds__(256) void vtpad_k(uint16_t* __restrict__ vt)
{
  int idx = blockIdx.x * 256 + threadIdx.x;          // < 1024*8*256
  int wh = idx >> 11, r = (idx >> 8) & 7, c = idx & 255;
  vt[((size_t)(wh * 80 + 72 + r)) * 256 + c] = 0;
}

// ---------------- weight transpose + pad + cast: Wt[Np][K] = W[k][c0+n] ----------------
__global__ __launch_bounds__(256) void wtrans_k(const float* __restrict__ W, uint16_t* __restrict__ Wt,
                                                int K, int N, int Np, int ldw, int c0)
{
  int idx = blockIdx.x * 256 + threadIdx.x;
  if (idx >= Np * K) return;
  int n = idx / K, k = idx - n * K;
  float v = (n < N) ? W[(size_t)k * ldw + c0 + n] : 0.0f;
  Wt[idx] = f2bf(v);
}

// ---------------- build extended MLP-down weight: m2Te[si][640][2400] ----------------
__global__ __launch_bounds__(256) void mk_m2te_k(const float* __restrict__ w2,
    const float* __restrict__ uw, const float* __restrict__ ub, uint16_t* __restrict__ m2Te)
{
  int idx = blockIdx.x * 256 + threadIdx.x;
  if (idx >= 2 * 640 * 2400) return;
  int si = idx / (640 * 2400);
  int rem = idx - si * 640 * 2400;
  int n = rem / 2400, k = rem - n * 2400;
  float v = 0.0f;
  if (n < 576){
    if (k < 2304) v = w2[(size_t)k * 576 + n];
    else if (k < 2368){
      int e = (k - 2304) >> 5, r = (k - 2304) & 31;
      v = uw[((size_t)(si * 2 + e) * 32 + r) * 576 + n];
    } else if (k < 2370){
      v = ub[(size_t)(si * 2 + (k - 2368)) * 576 + n];
    }
  }
  m2Te[idx] = f2bf(v);
}

// ---------------- build adapter phase-1 weight adT[si][128][576] + bias adB[si][128] ----------------
__global__ __launch_bounds__(256) void mk_adt_k(const float* __restrict__ dwn, const float* __restrict__ gw,
    const float* __restrict__ dbn, const float* __restrict__ gb,
    uint16_t* __restrict__ adT, float* __restrict__ adB)
{
  int idx = blockIdx.x * 256 + threadIdx.x;
  if (idx >= 2 * 128 * 576) return;
  int si = idx / (128 * 576);
  int rem = idx - si * 128 * 576;
  int n = rem / 576, k = rem - n * 576;
  float v = 0.0f;
  if (n < 64){
    int e = n >> 5, r = n & 31;
    v = dwn[((size_t)(si * 2 + e) * 576 + k) * 32 + r];
  } else if (n < 66){
    v = gw[(size_t)si * 1152 + k * 2 + (n - 64)];
  }
  adT[idx] = f2bf(v);
  if (k == 0){
    float bv = 0.0f;
    if (n < 64) bv = dbn[si * 64 + (n >> 5) * 32 + (n & 31)];
    else if (n < 66) bv = gb[si * 2 + (n - 64)];
    adB[si * 128 + n] = bv;
  }
}

// ---------------- combined pool bias pqB[1152] = [proj_b | qkv_b[0:576]] ----------------
__global__ __launch_bounds__(256) void mk_pqb_k(const float* __restrict__ pb, const float* __restrict__ qb,
                                                float* __restrict__ o)
{
  int i = blockIdx.x * 256 + threadIdx.x;
  if (i < 1152) o[i] = (i < 576) ? pb[i] : qb[i - 576];
}

// ---------------- LayerNorm (wave per token) -> bf16 out; input f32 or bf16 ----------------
template<typename TIN>
__global__ __launch_bounds__(256) void ln_k(const TIN* __restrict__ in0, const int D,
                                            const float* __restrict__ g, const float* __restrict__ bb,
                                            uint16_t* __restrict__ outp)
{
  const int token = blockIdx.x * 4 + (threadIdx.x >> 6);
  const int lane = threadIdx.x & 63;
  const TIN* in = in0 + (size_t)token * D;
  const int nf4 = D >> 2;
  f32x4 v[3];
  float s = 0.f, sq = 0.f;
#pragma unroll
  for (int i = 0; i < 3; ++i){
    const int c = lane + 64 * i;
    if (c < nf4){
      if constexpr (std::is_same<TIN, float>::value){
        v[i] = *(const f32x4*)(in + 4 * c);
      } else {
        u32x2 u = *(const u32x2*)((const uint16_t*)in + 4 * c);
        v[i][0] = bflo(u[0]); v[i][1] = bfhi(u[0]);
        v[i][2] = bflo(u[1]); v[i][3] = bfhi(u[1]);
      }
#pragma unroll
      for (int e = 0; e < 4; ++e){ s += v[i][e]; sq += v[i][e] * v[i][e]; }
    }
  }
#pragma unroll
  for (int off = 32; off; off >>= 1){
    s  += __shfl_xor(s, off);
    sq += __shfl_xor(sq, off);
  }
  const float mean = s / (float)D;
  const float var = sq / (float)D - mean * mean;
  const float inv = rsqrtf(var + 1e-6f);
  uint16_t* orow = outp + (size_t)token * D;
#pragma unroll
  for (int i = 0; i < 3; ++i){
    const int c = lane + 64 * i;
    if (c < nf4){
      float f0 = (v[i][0] - mean) * inv * g[4*c+0] + bb[4*c+0];
      float f1 = (v[i][1] - mean) * inv * g[4*c+1] + bb[4*c+1];
      float f2 = (v[i][2] - mean) * inv * g[4*c+2] + bb[4*c+2];
      float f3 = (v[i][3] - mean) * inv * g[4*c+3] + bb[4*c+3];
      u32x2 pk; pk[0] = pk2(f0, f1); pk[1] = pk2(f2, f3);
      *(u32x2*)(orow + 4 * c) = pk;
    }
  }
}

// ---------------- shared GEMM core: BMx128 tile, 2-buf __syncthreads (PROVEN r9 structure) ----------------
// Generalized to BM in {64,128,256}: A slices per stage = BM/64.
template<int BM>
DI void gemm_core(const uint16_t* __restrict__ A, const uint16_t* __restrict__ Bt,
                  const int K, char* smem, const int tid, f32x4 (*acc)[4])
{
  constexpr int MI = BM / 32;
  constexpr int NSA = BM / 64;         // A 16B-loads per thread per stage
  constexpr int ABUF = BM * 64;        // A bytes per buffer
  char* A0 = smem;
  char* A1 = smem + ABUF;
  char* B0 = smem + 2 * ABUF;
  char* B1 = smem + 2 * ABUF + 8192;
  const int lane = tid & 63;
  const int wid = tid >> 6;
  const int wm = (wid >> 1) * (BM / 2);
  const int wn = (wid & 1) * 64;
  const int r15 = lane & 15, kh = lane >> 4;
  const int rA0 = tid >> 2, c16 = tid & 3;
  const int kS = ((c16 ^ ((rA0 >> 1) & 3)) << 3);   // pre-swizzled k-offset (elements)
  // NOTE: (row+64s)>>1 & 3 == (row>>1)&3 since 64/2 % 4 == 0, so kS is slice-invariant.

  auto stage = [&](char* Ad, char* Bd, int t){
#pragma unroll
    for (int s = 0; s < NSA; ++s){
      const uint16_t* ga = A + (size_t)(rA0 + 64 * s) * K + t * 32 + kS;
#if USE_GLLDS
      gload_lds16(ga, Ad + tid * 16 + s * 4096);
#else
      *(u32x4*)(Ad + tid * 16 + s * 4096) = *(const u32x4*)ga;
#endif
    }
    const uint16_t* gb0 = Bt + (size_t)rA0 * K + t * 32 + kS;
    const uint16_t* gb1 = Bt + (size_t)(rA0 + 64) * K + t * 32 + kS;
#if USE_GLLDS
    gload_lds16(gb0, Bd + tid * 16);
    gload_lds16(gb1, Bd + tid * 16 + 4096);
#else
    *(u32x4*)(Bd + tid * 16)        = *(const u32x4*)gb0;
    *(u32x4*)(Bd + tid * 16 + 4096) = *(const u32x4*)gb1;
#endif
  };

  stage(A0, B0, 0);
  __syncthreads();
  const int nt = K >> 5;
  for (int t = 0; t < nt; ++t){
    char* Ac = (t & 1) ? A1 : A0;
    char* Bc = (t & 1) ? B1 : B0;
    if (t + 1 < nt) stage((t & 1) ? A0 : A1, (t & 1) ? B0 : B1, t + 1);
    bf16x8 af[MI], bfv[4];
#pragma unroll
    for (int i = 0; i < MI; ++i){
      int rowA = wm + i * 16 + r15;
      af[i] = *(const bf16x8*)(Ac + rowA * 64 + ((kh ^ ((rowA >> 1) & 3)) << 4));
    }
#pragma unroll
    for (int j = 0; j < 4; ++j){
      int rowB = wn + j * 16 + r15;
      bfv[j] = *(const bf16x8*)(Bc + rowB * 64 + ((kh ^ ((rowB >> 1) & 3)) << 4));
    }
#pragma unroll
    for (int i = 0; i < MI; ++i)
#pragma unroll
      for (int j = 0; j < 4; ++j)
        acc[i][j] = __builtin_amdgcn_mfma_f32_16x16x32_bf16(af[i], bfv[j], acc[i][j], 0, 0, 0);
    __syncthreads();
  }
}

// ---------------- merged pool(proj+q)+kv GEMM over A=xn, M=32768, K=288, BM=256 ----------------
// y<9: pooled proj+q (N=1152) -> sc,qp (IN-REGISTER 2x2 maxpool). y>=9: k,v -> kb, vt-scatter.
// BM=256: each wave owns 128 consecutive tokens = 2 image rows; vertical pool pair is
// acc[i] <-> acc[i+4] (rows +64), horizontal pair is tt {0,1} / {2,3} (adjacent x).
__global__ __launch_bounds__(256) void gemm_pkv_k(
    const uint16_t* __restrict__ xn, const uint16_t* __restrict__ pqT, const uint16_t* __restrict__ kvT,
    const float* __restrict__ pqB, const float* __restrict__ kvB,
    uint16_t* __restrict__ sc, uint16_t* __restrict__ qp,
    uint16_t* __restrict__ kb, uint16_t* __restrict__ vt)
{
  __shared__ __align__(16) char smem[49152];   // 2 x (16KB A + 8KB B)
  const int tid = threadIdx.x;
  const int m0 = blockIdx.x * 256;
  const int y = blockIdx.y;            // 0..17
  const bool pool = (y < 9);
  const int n0 = pool ? y * 128 : (y - 9) * 128;
  const uint16_t* Bt = (pool ? pqT : kvT) + (size_t)n0 * 288;
  f32x4 acc[8][4] = {};
  gemm_core<256>(xn + (size_t)m0 * 288, Bt, 288, smem, tid, acc);

  const int lane = tid & 63, wid = tid >> 6;
  const int wm = (wid >> 1) * 128, wn = (wid & 1) * 64;
  const int r15 = lane & 15, kh = lane >> 4;
  int coln[4];
#pragma unroll
  for (int j = 0; j < 4; ++j) coln[j] = n0 + wn + j * 16 + r15;

  if (pool){
    // pooled row = ((m0+wm)>>7)*32 + xh, xh = i*8 + kh*2 + tth
    const int prow0 = ((m0 + wm) >> 7) * 32;
    float bcol[4];
#pragma unroll
    for (int j = 0; j < 4; ++j) bcol[j] = pqB[coln[j]];
#pragma unroll
    for (int i = 0; i < 4; ++i)
#pragma unroll
      for (int tth = 0; tth < 2; ++tth){
        const int prow = prow0 + i * 8 + kh * 2 + tth;
        const size_t ro = (size_t)prow * 576;
#pragma unroll
        for (int j = 0; j < 4; ++j){
          float v = fmaxf(fmaxf(acc[i][j][2 * tth], acc[i][j][2 * tth + 1]),
                          fmaxf(acc[i + 4][j][2 * tth], acc[i + 4][j][2 * tth + 1])) + bcol[j];
          if (coln[j] < 576) sc[ro + coln[j]] = f2bf(v);
          else               qp[ro + coln[j] - 576] = f2bf(v);
        }
      }
  } else {
    float bcol[4];
#pragma unroll
    for (int j = 0; j < 4; ++j) bcol[j] = kvB[coln[j]];
#pragma unroll
    for (int i = 0; i < 8; ++i)
#pragma unroll
      for (int tt = 0; tt < 4; ++tt){
        const int gm = m0 + wm + i * 16 + kh * 4 + tt;
#pragma unroll
        for (int j = 0; j < 4; ++j){
          float v = acc[i][j][tt] + bcol[j];
          int n = coln[j];
          if (n < 576){
            kb[(size_t)gm * 576 + n] = f2bf(v);
          } else {
            int d = n - 576;
            int hh = d / 72, dd = d - hh * 72;
            int bimg = gm >> 12, yy = (gm >> 6) & 63, xx = gm & 63;
            int w = bimg * 16 + (yy >> 4) * 4 + (xx >> 4);
            int kl = (yy & 15) * 16 + (xx & 15);
            vt[((size_t)(w * 8 + hh) * 80 + dd) * 256 + kl] = f2bf(v);
          }
        }
      }
  }
}

// ---------------- BM=128 GEMM: attn-proj + shortcut -> x2b bf16 (merged M=16384) ----------------
__global__ __launch_bounds__(256) void gemm_add1_k(
    const uint16_t* __restrict__ ob, const uint16_t* __restrict__ aT, const float* __restrict__ bias,
    const uint16_t* __restrict__ sc, uint16_t* __restrict__ x2b)
{
  __shared__ __align__(16) char smem[32768];
  const int tid = threadIdx.x;
  const int m0 = blockIdx.x * 128;
  const int n0 = blockIdx.y * 128;
  f32x4 acc[4][4] = {};
  gemm_core<128>(ob + (size_t)m0 * 576, aT + (size_t)n0 * 576, 576, smem, tid, acc);

  const int lane = tid & 63, wid = tid >> 6;
  const int wm = (wid >> 1) * 64, wn = (wid & 1) * 64;
  const int r15 = lane & 15, kh = lane >> 4;
  int coln[4]; float bcol[4];
#pragma unroll
  for (int j = 0; j < 4; ++j){
    coln[j] = n0 + wn + j * 16 + r15;
    bcol[j] = (coln[j] < 576) ? bias[coln[j]] : 0.0f;
  }
#pragma unroll
  for (int i = 0; i < 4; ++i)
#pragma unroll
    for (int tt = 0; tt < 4; ++tt){
      const int gm = m0 + wm + i * 16 + kh * 4 + tt;
      const size_t ro = (size_t)gm * 576;
#pragma unroll
      for (int j = 0; j < 4; ++j){
        if (coln[j] < 576){
          float v = acc[i][j][tt] + bcol[j] + bflo(sc[ro + coln[j]]);
          x2b[ro + coln[j]] = f2bf(v);
        }
      }
    }
}

// ---------------- BM=128 merged GEMM: MLP-up(gelu) + adapter phase-1, K=576 (merged M=16384) ----------------
__global__ __launch_bounds__(256) void gemm_upad_k(
    const uint16_t* __restrict__ hb, const uint16_t* __restrict__ x2b,
    const uint16_t* __restrict__ m1T, const uint16_t* __restrict__ adT,
    const float* __restrict__ b1, const float* __restrict__ adB,
    uint16_t* __restrict__ mlpA)
{
  __shared__ __align__(16) char smem[32768];
  const int tid = threadIdx.x;
  const int m0 = blockIdx.x * 128;
  const int y = blockIdx.y;
  const bool up = (y < 18);
  const int si = m0 >> 13;             // stream of this M-tile
  const int n0 = up ? y * 128 : 0;
  const uint16_t* A = (up ? hb : x2b) + (size_t)m0 * 576;
  const uint16_t* Bt = up ? (m1T + (size_t)n0 * 576) : (adT + (size_t)si * 128 * 576);
  f32x4 acc[4][4] = {};
  gemm_core<128>(A, Bt, 576, smem, tid, acc);

  const int lane = tid & 63, wid = tid >> 6;
  const int wm = (wid >> 1) * 64, wn = (wid & 1) * 64;
  const int r15 = lane & 15, kh = lane >> 4;

  if (up){
#pragma unroll
    for (int i = 0; i < 4; ++i)
#pragma unroll
      for (int tt = 0; tt < 4; ++tt){
        const int gm = m0 + wm + i * 16 + kh * 4 + tt;
#pragma unroll
        for (int j = 0; j < 4; ++j){
          int c = n0 + wn + j * 16 + r15;
          float v = acc[i][j][tt] + b1[c];
          mlpA[(size_t)gm * 2400 + c] = f2bf(geluf(v));
        }
      }
  } else {
    const float* adBp = adB + si * 128;
    float* gl = (float*)smem;   // [128][2] gate logits
#pragma unroll
    for (int i = 0; i < 4; ++i)
#pragma unroll
      for (int j = 0; j < 4; ++j){
        int c = wn + j * 16 + r15;
        if (c == 64 || c == 65){
#pragma unroll
          for (int tt = 0; tt < 4; ++tt){
            int rr2 = wm + i * 16 + kh * 4 + tt;
            gl[rr2 * 2 + (c - 64)] = acc[i][j][tt] + adBp[c];
          }
        }
      }
    __syncthreads();
#pragma unroll
    for (int i = 0; i < 4; ++i)
#pragma unroll
      for (int tt = 0; tt < 4; ++tt){
        int rr2 = wm + i * 16 + kh * 4 + tt;
        int gm = m0 + rr2;
        float l0 = gl[rr2 * 2], l1 = gl[rr2 * 2 + 1];
        float mx = fmaxf(l0, l1);
        float e0 = __expf(l0 - mx), e1 = __expf(l1 - mx);
        float inv = 0.5f / (e0 + e1);
#pragma unroll
        for (int j = 0; j < 4; ++j){
          int c = wn + j * 16 + r15;
          if (c < 96){
            float val;
            if (c < 64){
              float g = ((c >> 5) == 0 ? e0 : e1) * inv;
              val = g * geluf(acc[i][j][tt] + adBp[c]);
            } else if (c == 64) val = e0 * inv;
            else if (c == 65) val = e1 * inv;
            else val = 0.0f;
            mlpA[(size_t)gm * 2400 + 2304 + c] = f2bf(val);
          }
        }
      }
  }
}

// ---------------- BM=128 GEMM: MLP-down + adapter-up + x2 -> out f32 (K=2400, merged M=16384) ----------------
__global__ __launch_bounds__(256) void gemm_addf_k(
    const uint16_t* __restrict__ mlpA, const uint16_t* __restrict__ m2Te, const float* __restrict__ bias,
    const uint16_t* __restrict__ x2b, float* __restrict__ outf)
{
  __shared__ __align__(16) char smem[32768];
  const int tid = threadIdx.x;
  const int m0 = blockIdx.x * 128;
  const int n0 = blockIdx.y * 128;
  const int si = m0 >> 13;
  f32x4 acc[4][4] = {};
  gemm_core<128>(mlpA + (size_t)m0 * 2400, m2Te + (size_t)si * 640 * 2400 + (size_t)n0 * 2400,
                 2400, smem, tid, acc);

  const int lane = tid & 63, wid = tid >> 6;
  const int wm = (wid >> 1) * 64, wn = (wid & 1) * 64;
  const int r15 = lane & 15, kh = lane >> 4;
  int coln[4]; float bcol[4];
#pragma unroll
  for (int j = 0; j < 4; ++j){
    coln[j] = n0 + wn + j * 16 + r15;
    bcol[j] = (coln[j] < 576) ? bias[coln[j]] : 0.0f;
  }
#pragma unroll
  for (int i = 0; i < 4; ++i)
#pragma unroll
    for (int tt = 0; tt < 4; ++tt){
      const int gm = m0 + wm + i * 16 + kh * 4 + tt;
      const size_t ro = (size_t)gm * 576;
#pragma unroll
      for (int j = 0; j < 4; ++j){
        if (coln[j] < 576){
          float v = acc[i][j][tt] + bcol[j] + bflo(x2b[ro + coln[j]]);
          outf[ro + coln[j]] = v;
        }
      }
    }
}

// ---------------- MFMA windowed attention: 2 waves per (window, head), key-split + combine ----------------
__global__ __launch_bounds__(128) void attn_mfma_k(
    const uint16_t* __restrict__ qp,   // [8192][576] pooled q (unscaled)
    const uint16_t* __restrict__ kb,   // [32768][576] K
    const uint16_t* __restrict__ vt,   // [1024][80][256] V^T per (window,head), rows 72..79 zero
    uint16_t* __restrict__ o)          // [8192][576]
{
  __shared__ float comb[64][88];       // wave1's m[4], l[4], acco[80]
  const int tid = threadIdx.x;
  const int wave = tid >> 6;
  const int lane = tid & 63;
  const int r15 = lane & 15;
  const int kh = lane >> 4;
  const int bid = blockIdx.x;          // 0..1023
  const int h = bid & 7;
  const int w = bid >> 3;
  const int b = w >> 4;
  const int wy = (w >> 2) & 3;
  const int wx = w & 3;

  const u32x4 ZU = {0, 0, 0, 0};
  const bf16x8 Z8 = __builtin_bit_cast(bf16x8, ZU);
  const float scale = 0.11785113019775793f;  // 1/sqrt(72)

  bf16x8 qf[4][3];
  int qrow[4];
#pragma unroll
  for (int j = 0; j < 4; ++j){
    int q = j * 16 + r15;
    int y = wy * 8 + (q >> 3), x = wx * 8 + (q & 7);
    qrow[j] = b * 1024 + y * 32 + x;
    const uint16_t* qpr = qp + (size_t)qrow[j] * 576 + h * 72;
    qf[j][0] = *(const bf16x8*)(qpr + kh * 8);
    qf[j][1] = *(const bf16x8*)(qpr + 32 + kh * 8);
    qf[j][2] = (kh == 0) ? *(const bf16x8*)(qpr + 64) : Z8;
  }

  float m[4], l[4];
#pragma unroll
  for (int j = 0; j < 4; ++j){ m[j] = -INFINITY; l[j] = 0.0f; }
  f32x4 acco[5][4] = {};
  const size_t vtbase = (size_t)(w * 8 + h) * 80 * 256;

#pragma unroll
  for (int t2 = 0; t2 < 2; ++t2){
    const int t = wave * 2 + t2;       // wave0: tiles 0,1; wave1: tiles 2,3
    f32x4 accs[4][4] = {};
#pragma unroll
    for (int i = 0; i < 4; ++i){
      const uint16_t* kr = kb + (size_t)(b * 4096 + (wy * 16 + t * 4 + i) * 64 + wx * 16 + r15) * 576 + h * 72;
      bf16x8 kf0 = *(const bf16x8*)(kr + kh * 8);
      bf16x8 kf1 = *(const bf16x8*)(kr + 32 + kh * 8);
      bf16x8 kf2 = (kh == 0) ? *(const bf16x8*)(kr + 64) : Z8;
#pragma unroll
      for (int j = 0; j < 4; ++j){
        accs[i][j] = __builtin_amdgcn_mfma_f32_16x16x32_bf16(kf0, qf[j][0], accs[i][j], 0, 0, 0);
        accs[i][j] = __builtin_amdgcn_mfma_f32_16x16x32_bf16(kf1, qf[j][1], accs[i][j], 0, 0, 0);
        accs[i][j] = __builtin_amdgcn_mfma_f32_16x16x32_bf16(kf2, qf[j][2], accs[i][j], 0, 0, 0);
      }
    }
#pragma unroll
    for (int j = 0; j < 4; ++j){
      float mx = -INFINITY;
#pragma unroll
      for (int i = 0; i < 4; ++i)
#pragma unroll
        for (int tt = 0; tt < 4; ++tt){
          float sv = accs[i][j][tt] * scale;
          accs[i][j][tt] = sv;
          mx = fmaxf(mx, sv);
        }
      mx = fmaxf(mx, __shfl_xor(mx, 16));
      mx = fmaxf(mx, __shfl_xor(mx, 32));
      float nm = fmaxf(m[j], mx);
      float f = __expf(m[j] - nm);
      m[j] = nm;
      l[j] *= f;
#pragma unroll
      for (int i2 = 0; i2 < 5; ++i2) acco[i2][j] *= f;
      float ls = 0.0f;
#pragma unroll
      for (int i = 0; i < 4; ++i)
#pragma unroll
        for (int tt = 0; tt < 4; ++tt){
          float p = __expf(accs[i][j][tt] - nm);
          accs[i][j][tt] = p;
          ls += p;
        }
      ls += __shfl_xor(ls, 16);
      ls += __shfl_xor(ls, 32);
      l[j] += ls;
    }
    uint32_t pw[4][4][2];
#pragma unroll
    for (int i = 0; i < 4; ++i)
#pragma unroll
      for (int j = 0; j < 4; ++j){
        pw[i][j][0] = pk2(accs[i][j][0], accs[i][j][1]);
        pw[i][j][1] = pk2(accs[i][j][2], accs[i][j][3]);
      }
#pragma unroll
    for (int ks = 0; ks < 2; ++ks){
      bf16x8 pb[4];
#pragma unroll
      for (int j = 0; j < 4; ++j){
        u32x4 u = {pw[2 * ks][j][0], pw[2 * ks][j][1], pw[2 * ks + 1][j][0], pw[2 * ks + 1][j][1]};
        pb[j] = __builtin_bit_cast(bf16x8, u);
      }
#pragma unroll
      for (int i2 = 0; i2 < 5; ++i2){
        const uint16_t* vr = vt + vtbase + (size_t)(i2 * 16 + r15) * 256 + t * 64 + ks * 32 + kh * 4;
        u32x2 lo = *(const u32x2*)(vr);
        u32x2 hi = *(const u32x2*)(vr + 16);
        u32x4 av = {lo[0], lo[1], hi[0], hi[1]};
        bf16x8 va = __builtin_bit_cast(bf16x8, av);
#pragma unroll
        for (int j = 0; j < 4; ++j)
          acco[i2][j] = __builtin_amdgcn_mfma_f32_16x16x32_bf16(va, pb[j], acco[i2][j], 0, 0, 0);
      }
    }
  }

  // flash-combine the two waves' partials, wave0 writes
  if (wave == 1){
#pragma unroll
    for (int j = 0; j < 4; ++j){ comb[lane][j] = m[j]; comb[lane][4 + j] = l[j]; }
#pragma unroll
    for (int i2 = 0; i2 < 5; ++i2)
#pragma unroll
      for (int j = 0; j < 4; ++j)
#pragma unroll
        for (int tt = 0; tt < 4; ++tt)
          comb[lane][8 + (i2 * 4 + j) * 4 + tt] = acco[i2][j][tt];
  }
  __syncthreads();
  if (wave == 0){
    float fs0[4], fs1[4];
#pragma unroll
    for (int j = 0; j < 4; ++j){
      float m1v = comb[lane][j], l1v = comb[lane][4 + j];
      float nm = fmaxf(m[j], m1v);
      fs0[j] = __expf(m[j] - nm);
      fs1[j] = __expf(m1v - nm);
      l[j] = l[j] * fs0[j] + l1v * fs1[j];
    }
#pragma unroll
    for (int j = 0; j < 4; ++j){
      float inv = 1.0f / l[j];
      uint16_t* orow = o + (size_t)qrow[j] * 576 + h * 72;
#pragma unroll
      for (int i2 = 0; i2 < 5; ++i2)
#pragma unroll
        for (int tt = 0; tt < 4; ++tt){
          int d = i2 * 16 + kh * 4 + tt;
          if (d < 72){
            float ov = acco[i2][j][tt] * fs0[j] + comb[lane][8 + (i2 * 4 + j) * 4 + tt] * fs1[j];
            orow[d] = f2bf(ov * inv);
          }
        }
    }
  }
}

extern "C" void kernel_launch(void* const* d_in, const int* in_sizes, int n_in,
                              void* d_out, int out_size, void* d_ws, size_t ws_size,
                              hipStream_t stream)
{
  (void)in_sizes; (void)n_in; (void)out_size; (void)ws_size;
  const float* srcs[2] = { (const float*)d_in[0], (const float*)d_in[1] };
  const float* n1g    = (const float*)d_in[2];
  const float* n1b    = (const float*)d_in[3];
  const float* proj_w = (const float*)d_in[4];
  const float* proj_b = (const float*)d_in[5];
  const float* qkv_w  = (const float*)d_in[6];
  const float* qkv_b  = (const float*)d_in[7];
  const float* ap_w   = (const float*)d_in[8];
  const float* ap_b   = (const float*)d_in[9];
  const float* n2g    = (const float*)d_in[10];
  const float* n2b    = (const float*)d_in[11];
  const float* w1     = (const float*)d_in[12];
  const float* b1     = (const float*)d_in[13];
  const float* w2     = (const float*)d_in[14];
  const float* b2     = (const float*)d_in[15];
  const float* gw     = (const float*)d_in[16];
  const float* gb     = (const float*)d_in[17];
  const float* dwn    = (const float*)d_in[18];
  const float* dbn    = (const float*)d_in[19];
  const float* uw     = (const float*)d_in[20];
  const float* ub     = (const float*)d_in[21];

  char* ws = (char*)d_ws;
  size_t off = 0;
  auto alloc = [&](size_t bytes){ size_t o = off; off += (bytes + 255) & ~(size_t)255; return o; };

  // shared weights (bf16) — ~11.2 MB
  uint16_t* pqT   = (uint16_t*)(ws + alloc((size_t)1152 * 288 * 2));  // [proj 576 | q 576]
  float*    pqB   = (float*)(ws + alloc((size_t)1152 * 4));
  uint16_t* kvT   = (uint16_t*)(ws + alloc((size_t)1152 * 288 * 2));
  uint16_t* aT    = (uint16_t*)(ws + alloc((size_t)640 * 576 * 2));
  uint16_t* m1T   = (uint16_t*)(ws + alloc((size_t)2304 * 576 * 2));
  uint16_t* m2Te  = (uint16_t*)(ws + alloc((size_t)2 * 640 * 2400 * 2));
  uint16_t* adT   = (uint16_t*)(ws + alloc((size_t)2 * 128 * 576 * 2));
  float*    adB   = (float*)(ws + alloc((size_t)2 * 128 * 4));
  // activations (total ws ~203 MB)
  uint16_t* xn   = (uint16_t*)(ws + alloc((size_t)32768 * 288 * 2));   // per-stream reuse
  uint16_t* sc2  = (uint16_t*)(ws + alloc((size_t)16384 * 576 * 2));   // both streams
  size_t oQP = alloc((size_t)16384 * 576 * 2);       // qp halves; later x2b merged
  uint16_t* qp2  = (uint16_t*)(ws + oQP);
  uint16_t* x2b  = (uint16_t*)(ws + oQP);
  uint16_t* kb   = (uint16_t*)(ws + alloc((size_t)32768 * 576 * 2));   // per-stream reuse
  size_t oVT = alloc((size_t)16384 * 2400 * 2);      // vt (41.9MB, reuse) ; later mlpA [16384][2400]
  uint16_t* vt   = (uint16_t*)(ws + oVT);
  uint16_t* mlpA = (uint16_t*)(ws + oVT);
  size_t oOB = alloc((size_t)16384 * 576 * 2);       // ob both streams; later hb merged
  uint16_t* ob2  = (uint16_t*)(ws + oOB);
  uint16_t* hb2  = (uint16_t*)(ws + oOB);

  // weight prep (once)
  wtrans_k<<<(576 * 288 + 255) / 256, 256, 0, stream>>>(proj_w, pqT, 288, 576, 576, 576, 0);
  wtrans_k<<<(576 * 288 + 255) / 256, 256, 0, stream>>>(qkv_w, pqT + (size_t)576 * 288, 288, 576, 576, 1728, 0);
  mk_pqb_k<<<5, 256, 0, stream>>>(proj_b, qkv_b, pqB);
  wtrans_k<<<(1152 * 288 + 255) / 256, 256, 0, stream>>>(qkv_w, kvT, 288, 1152, 1152, 1728, 576);
  wtrans_k<<<(640 * 576 + 255) / 256, 256, 0, stream>>>(ap_w, aT, 576, 576, 640, 576, 0);
  wtrans_k<<<(2304 * 576 + 255) / 256, 256, 0, stream>>>(w1, m1T, 576, 2304, 2304, 2304, 0);
  mk_m2te_k<<<(2 * 640 * 2400 + 255) / 256, 256, 0, stream>>>(w2, uw, ub, m2Te);
  mk_adt_k<<<(2 * 128 * 576 + 255) / 256, 256, 0, stream>>>(dwn, gw, dbn, gb, adT, adB);

  // -------- frontend per stream --------
  for (int si = 0; si < 2; ++si){
    const size_t half = (size_t)si * 8192 * 576;

    // LN1 -> xn bf16 [32768 x 288]
    ln_k<float><<<8192, 256, 0, stream>>>(srcs[si], 288, n1g, n1b, xn);

    // zero V^T pad rows (72..79 of each slab; mlpA aliased last call/stream)
    vtpad_k<<<(1024 * 8 * 256) / 256, 256, 0, stream>>>(vt);

    // merged pool(proj+q) + kv GEMM (BM=256, in-register pool) -> sc, qp, kb, vt
    gemm_pkv_k<<<dim3(128, 18), 256, 0, stream>>>(xn, pqT, kvT, pqB, qkv_b + 576,
                                                  sc2 + half, qp2 + half, kb, vt);

    // MFMA windowed attention (2-wave key-split) -> ob bf16
    attn_mfma_k<<<1024, 128, 0, stream>>>(qp2 + half, kb, vt, ob2 + half);
  }

  // -------- backend merged over both streams (M=16384, BM=128) --------
  // attn out-proj + shortcut -> x2b bf16 (aliases qp2, dead after attn)
  gemm_add1_k<<<dim3(128, 5), 256, 0, stream>>>(ob2, aT, ap_b, sc2, x2b);

  // LN2 -> hb bf16 (aliases ob2, dead after add1)
  ln_k<uint16_t><<<4096, 256, 0, stream>>>(x2b, 576, n2g, n2b, hb2);

  // MLP up + gelu (cols 0..2303) + adapter phase-1 (cols 2304..2399) -> mlpA (aliases vt)
  gemm_upad_k<<<dim3(128, 19), 256, 0, stream>>>(hb2, x2b, m1T, adT, b1, adB, mlpA);

  // MLP down + adapter up + x2 -> out f32 (K=2400 extended)
  gemm_addf_k<<<dim3(128, 5), 256, 0, stream>>>(mlpA, m2Te, b2, x2b, (float*)d_out);
}

// Round 13
// 557.712 us; speedup vs baseline: 1.0941x; 1.0941x over previous
//
#include <hip/hip_runtime.h>
#include <cstdint>
#include <math.h>
#include <type_traits>

typedef __bf16 bf16_t;
typedef __bf16 bf16x8 __attribute__((ext_vector_type(8)));
typedef float f32x4 __attribute__((ext_vector_type(4)));
typedef uint32_t u32x4 __attribute__((ext_vector_type(4)));
typedef uint32_t u32x2 __attribute__((ext_vector_type(2)));

#define DI __device__ __forceinline__

DI float bflo(uint32_t u){ return __builtin_bit_cast(float, (uint32_t)(u << 16)); }
DI float bfhi(uint32_t u){ return __builtin_bit_cast(float, (uint32_t)(u & 0xffff0000u)); }
DI uint16_t f2bf(float f){ bf16_t h = (bf16_t)f; return __builtin_bit_cast(uint16_t, h); }
DI uint32_t pk2(float a, float b){ return (uint32_t)f2bf(a) | ((uint32_t)f2bf(b) << 16); }
// gelu(tanh-approx) == x * sigmoid(2u): HW exp+rcp instead of libm tanhf.
DI float geluf(float x){
  float t = x * x;
  float p = fmaf(t, 0.0356774081f, 0.7978845608f);
  float e = __expf(-2.0f * x * p);
  return x * __builtin_amdgcn_rcpf(1.0f + e);
}

#if defined(__has_builtin)
#if __has_builtin(__builtin_amdgcn_global_load_lds)
#define USE_GLLDS 1
#endif
#endif

#if USE_GLLDS
DI void gload_lds16(const void* g, void* l){
  __builtin_amdgcn_global_load_lds((__attribute__((address_space(1))) void*)g,
                                   (__attribute__((address_space(3))) void*)l, 16, 0, 0);
}
#endif

// ---------------- weight transpose + pad + cast: Wt[Np][K] = W[k][c0+n] ----------------
__global__ __launch_bounds__(256) void wtrans_k(const float* __restrict__ W, uint16_t* __restrict__ Wt,
                                                int K, int N, int Np, int ldw, int c0)
{
  int idx = blockIdx.x * 256 + threadIdx.x;
  if (idx >= Np * K) return;
  int n = idx / K, k = idx - n * K;
  float v = (n < N) ? W[(size_t)k * ldw + c0 + n] : 0.0f;
  Wt[idx] = f2bf(v);
}

// ---------------- build extended MLP-down weight: m2Te[si][640][2400] ----------------
__global__ __launch_bounds__(256) void mk_m2te_k(const float* __restrict__ w2,
    const float* __restrict__ uw, const float* __restrict__ ub, uint16_t* __restrict__ m2Te)
{
  int idx = blockIdx.x * 256 + threadIdx.x;
  if (idx >= 2 * 640 * 2400) return;
  int si = idx / (640 * 2400);
  int rem = idx - si * 640 * 2400;
  int n = rem / 2400, k = rem - n * 2400;
  float v = 0.0f;
  if (n < 576){
    if (k < 2304) v = w2[(size_t)k * 576 + n];
    else if (k < 2368){
      int e = (k - 2304) >> 5, r = (k - 2304) & 31;
      v = uw[((size_t)(si * 2 + e) * 32 + r) * 576 + n];
    } else if (k < 2370){
      v = ub[(size_t)(si * 2 + (k - 2368)) * 576 + n];
    }
  }
  m2Te[idx] = f2bf(v);
}

// ---------------- build adapter phase-1 weight adT[si][128][576] + bias adB[si][128] ----------------
__global__ __launch_bounds__(256) void mk_adt_k(const float* __restrict__ dwn, const float* __restrict__ gw,
    const float* __restrict__ dbn, const float* __restrict__ gb,
    uint16_t* __restrict__ adT, float* __restrict__ adB)
{
  int idx = blockIdx.x * 256 + threadIdx.x;
  if (idx >= 2 * 128 * 576) return;
  int si = idx / (128 * 576);
  int rem = idx - si * 128 * 576;
  int n = rem / 576, k = rem - n * 576;
  float v = 0.0f;
  if (n < 64){
    int e = n >> 5, r = n & 31;
    v = dwn[((size_t)(si * 2 + e) * 576 + k) * 32 + r];
  } else if (n < 66){
    v = gw[(size_t)si * 1152 + k * 2 + (n - 64)];
  }
  adT[idx] = f2bf(v);
  if (k == 0){
    float bv = 0.0f;
    if (n < 64) bv = dbn[si * 64 + (n >> 5) * 32 + (n & 31)];
    else if (n < 66) bv = gb[si * 2 + (n - 64)];
    adB[si * 128 + n] = bv;
  }
}

// ---------------- combined pool bias pqB[1152] = [proj_b | qkv_b[0:576]] ----------------
__global__ __launch_bounds__(256) void mk_pqb_k(const float* __restrict__ pb, const float* __restrict__ qb,
                                                float* __restrict__ o)
{
  int i = blockIdx.x * 256 + threadIdx.x;
  if (i < 1152) o[i] = (i < 576) ? pb[i] : qb[i - 576];
}

// ---------------- LayerNorm (wave per token) -> bf16 out; input f32 or bf16 ----------------
template<typename TIN>
__global__ __launch_bounds__(256) void ln_k(const TIN* __restrict__ in0, const int D,
                                            const float* __restrict__ g, const float* __restrict__ bb,
                                            uint16_t* __restrict__ outp)
{
  const int token = blockIdx.x * 4 + (threadIdx.x >> 6);
  const int lane = threadIdx.x & 63;
  const TIN* in = in0 + (size_t)token * D;
  const int nf4 = D >> 2;
  f32x4 v[3];
  float s = 0.f, sq = 0.f;
#pragma unroll
  for (int i = 0; i < 3; ++i){
    const int c = lane + 64 * i;
    if (c < nf4){
      if constexpr (std::is_same<TIN, float>::value){
        v[i] = *(const f32x4*)(in + 4 * c);
      } else {
        u32x2 u = *(const u32x2*)((const uint16_t*)in + 4 * c);
        v[i][0] = bflo(u[0]); v[i][1] = bfhi(u[0]);
        v[i][2] = bflo(u[1]); v[i][3] = bfhi(u[1]);
      }
#pragma unroll
      for (int e = 0; e < 4; ++e){ s += v[i][e]; sq += v[i][e] * v[i][e]; }
    }
  }
#pragma unroll
  for (int off = 32; off; off >>= 1){
    s  += __shfl_xor(s, off);
    sq += __shfl_xor(sq, off);
  }
  const float mean = s / (float)D;
  const float var = sq / (float)D - mean * mean;
  const float inv = rsqrtf(var + 1e-6f);
  uint16_t* orow = outp + (size_t)token * D;
#pragma unroll
  for (int i = 0; i < 3; ++i){
    const int c = lane + 64 * i;
    if (c < nf4){
      float f0 = (v[i][0] - mean) * inv * g[4*c+0] + bb[4*c+0];
      float f1 = (v[i][1] - mean) * inv * g[4*c+1] + bb[4*c+1];
      float f2 = (v[i][2] - mean) * inv * g[4*c+2] + bb[4*c+2];
      float f3 = (v[i][3] - mean) * inv * g[4*c+3] + bb[4*c+3];
      u32x2 pk; pk[0] = pk2(f0, f1); pk[1] = pk2(f2, f3);
      *(u32x2*)(orow + 4 * c) = pk;
    }
  }
}

// ---------------- shared GEMM core: BMx128 tile, 2-buf __syncthreads, compile-time K ----------------
template<int BM, int KK>
DI void gemm_core(const uint16_t* __restrict__ A, const uint16_t* __restrict__ Bt,
                  char* smem, const int tid, f32x4 (*acc)[4])
{
  constexpr int MI = BM / 32;
  constexpr int ABUF = BM * 64;        // A bytes per buffer
  constexpr int nt = KK >> 5;
  char* A0 = smem;
  char* A1 = smem + ABUF;
  char* B0 = smem + 2 * ABUF;
  char* B1 = smem + 2 * ABUF + 8192;
  const int lane = tid & 63;
  const int wid = tid >> 6;
  const int wm = (wid >> 1) * (BM / 2);
  const int wn = (wid & 1) * 64;
  const int r15 = lane & 15, kh = lane >> 4;
  const int rA0 = tid >> 2, c16 = tid & 3;
  const int kS = ((c16 ^ ((rA0 >> 1) & 3)) << 3);   // pre-swizzled k-offset (elements)

  auto stage = [&](char* Ad, char* Bd, int t){
    const uint16_t* ga0 = A + (size_t)rA0 * KK + t * 32 + kS;
    const uint16_t* gb0 = Bt + (size_t)rA0 * KK + t * 32 + kS;
    const uint16_t* gb1 = Bt + (size_t)(rA0 + 64) * KK + t * 32 + kS;
#if USE_GLLDS
    gload_lds16(ga0, Ad + tid * 16);
    gload_lds16(gb0, Bd + tid * 16);
    gload_lds16(gb1, Bd + tid * 16 + 4096);
    if constexpr (BM == 128){
      const uint16_t* ga1 = A + (size_t)(rA0 + 64) * KK + t * 32 + kS;
      gload_lds16(ga1, Ad + tid * 16 + 4096);
    }
#else
    *(u32x4*)(Ad + tid * 16)        = *(const u32x4*)ga0;
    *(u32x4*)(Bd + tid * 16)        = *(const u32x4*)gb0;
    *(u32x4*)(Bd + tid * 16 + 4096) = *(const u32x4*)gb1;
    if constexpr (BM == 128){
      const uint16_t* ga1 = A + (size_t)(rA0 + 64) * KK + t * 32 + kS;
      *(u32x4*)(Ad + tid * 16 + 4096) = *(const u32x4*)ga1;
    }
#endif
  };

  stage(A0, B0, 0);
  __syncthreads();
  for (int t = 0; t < nt; ++t){
    char* Ac = (t & 1) ? A1 : A0;
    char* Bc = (t & 1) ? B1 : B0;
    if (t + 1 < nt) stage((t & 1) ? A0 : A1, (t & 1) ? B0 : B1, t + 1);
    bf16x8 af[MI], bfv[4];
#pragma unroll
    for (int i = 0; i < MI; ++i){
      int rowA = wm + i * 16 + r15;
      af[i] = *(const bf16x8*)(Ac + rowA * 64 + ((kh ^ ((rowA >> 1) & 3)) << 4));
    }
#pragma unroll
    for (int j = 0; j < 4; ++j){
      int rowB = wn + j * 16 + r15;
      bfv[j] = *(const bf16x8*)(Bc + rowB * 64 + ((kh ^ ((rowB >> 1) & 3)) << 4));
    }
#pragma unroll
    for (int i = 0; i < MI; ++i)
#pragma unroll
      for (int j = 0; j < 4; ++j)
        acc[i][j] = __builtin_amdgcn_mfma_f32_16x16x32_bf16(af[i], bfv[j], acc[i][j], 0, 0, 0);
    __syncthreads();
  }
}

// ---------------- merged pool(proj+q)+kv GEMM over A=xn, M=32768, K=288 (BM=128, r10-proven) ----------------
// y<9: pooled proj+q (N=1152) -> sc,qp. y>=9: k,v (N=1152) -> kb, vt-scatter.
__global__ __launch_bounds__(256) void gemm_pkv_k(
    const uint16_t* __restrict__ xn, const uint16_t* __restrict__ pqT, const uint16_t* __restrict__ kvT,
    const float* __restrict__ pqB, const float* __restrict__ kvB,
    uint16_t* __restrict__ sc, uint16_t* __restrict__ qp,
    uint16_t* __restrict__ kb, uint16_t* __restrict__ vt)
{
  __shared__ __align__(16) char smem[34816];   // gemm core 32KB; pool epilogue Cp 128x136x2
  const int tid = threadIdx.x;
  const int m0 = blockIdx.x * 128;
  const int y = blockIdx.y;            // 0..17
  const bool pool = (y < 9);
  const int n0 = pool ? y * 128 : (y - 9) * 128;
  const uint16_t* Bt = (pool ? pqT : kvT) + (size_t)n0 * 288;
  f32x4 acc[4][4] = {};
  gemm_core<128, 288>(xn + (size_t)m0 * 288, Bt, smem, tid, acc);

  const int lane = tid & 63, wid = tid >> 6;
  const int wm = (wid >> 1) * 64, wn = (wid & 1) * 64;
  const int r15 = lane & 15, kh = lane >> 4;

  if (pool){
    uint16_t* Cp = (uint16_t*)smem;    // stride 136 breaks the 8-way write aliasing
#pragma unroll
    for (int i = 0; i < 4; ++i)
#pragma unroll
      for (int j = 0; j < 4; ++j)
#pragma unroll
        for (int tt = 0; tt < 4; ++tt){
          int rr2 = wm + i * 16 + kh * 4 + tt;
          int cc = wn + j * 16 + r15;
          Cp[rr2 * 136 + cc] = f2bf(acc[i][j][tt]);
        }
    __syncthreads();
    const int orow0 = m0 >> 2;
#pragma unroll
    for (int e2 = 0; e2 < 16; ++e2){
      int idx = tid + 256 * e2;
      int X = idx >> 7, c = idx & 127;
      int gn = n0 + c;
      float v0 = bflo(Cp[(2 * X) * 136 + c]);
      float v1 = bflo(Cp[(2 * X + 1) * 136 + c]);
      float v2 = bflo(Cp[(64 + 2 * X) * 136 + c]);
      float v3 = bflo(Cp[(65 + 2 * X) * 136 + c]);
      float v = fmaxf(fmaxf(v0, v1), fmaxf(v2, v3)) + pqB[gn];
      if (gn < 576)
        sc[(size_t)(orow0 + X) * 576 + gn] = f2bf(v);
      else
        qp[(size_t)(orow0 + X) * 576 + (gn - 576)] = f2bf(v);
    }
  } else {
    int coln[4]; float bcol[4];
#pragma unroll
    for (int j = 0; j < 4; ++j){
      coln[j] = n0 + wn + j * 16 + r15;
      bcol[j] = kvB[coln[j]];
    }
#pragma unroll
    for (int i = 0; i < 4; ++i)
#pragma unroll
      for (int tt = 0; tt < 4; ++tt){
        const int gm = m0 + wm + i * 16 + kh * 4 + tt;
#pragma unroll
        for (int j = 0; j < 4; ++j){
          float v = acc[i][j][tt] + bcol[j];
          int n = coln[j];
          if (n < 576){
            kb[(size_t)gm * 576 + n] = f2bf(v);
          } else {
            int d = n - 576;
            int hh = d / 72, dd = d - hh * 72;
            int bimg = gm >> 12, yy = (gm >> 6) & 63, xx = gm & 63;
            int w = bimg * 16 + (yy >> 4) * 4 + (xx >> 4);
            int kl = (yy & 15) * 16 + (xx & 15);
            vt[((size_t)(w * 8 + hh) * 80 + dd) * 256 + kl] = f2bf(v);
          }
        }
      }
  }
}

// ---------------- BM=128 GEMM: attn-proj + shortcut -> x2b bf16 (merged M=16384) ----------------
__global__ __launch_bounds__(256) void gemm_add1_k(
    const uint16_t* __restrict__ ob, const uint16_t* __restrict__ aT, const float* __restrict__ bias,
    const uint16_t* __restrict__ sc, uint16_t* __restrict__ x2b)
{
  __shared__ __align__(16) char smem[32768];
  const int tid = threadIdx.x;
  const int m0 = blockIdx.x * 128;
  const int n0 = blockIdx.y * 128;
  f32x4 acc[4][4] = {};
  gemm_core<128, 576>(ob + (size_t)m0 * 576, aT + (size_t)n0 * 576, smem, tid, acc);

  const int lane = tid & 63, wid = tid >> 6;
  const int wm = (wid >> 1) * 64, wn = (wid & 1) * 64;
  const int r15 = lane & 15, kh = lane >> 4;
  int coln[4]; float bcol[4];
#pragma unroll
  for (int j = 0; j < 4; ++j){
    coln[j] = n0 + wn + j * 16 + r15;
    bcol[j] = (coln[j] < 576) ? bias[coln[j]] : 0.0f;
  }
#pragma unroll
  for (int i = 0; i < 4; ++i)
#pragma unroll
    for (int tt = 0; tt < 4; ++tt){
      const int gm = m0 + wm + i * 16 + kh * 4 + tt;
      const size_t ro = (size_t)gm * 576;
#pragma unroll
      for (int j = 0; j < 4; ++j){
        if (coln[j] < 576){
          float v = acc[i][j][tt] + bcol[j] + bflo(sc[ro + coln[j]]);
          x2b[ro + coln[j]] = f2bf(v);
        }
      }
    }
}

// ---------------- BM=128 merged GEMM: MLP-up(gelu) + adapter phase-1, K=576 (merged M=16384) ----------------
__global__ __launch_bounds__(256) void gemm_upad_k(
    const uint16_t* __restrict__ hb, const uint16_t* __restrict__ x2b,
    const uint16_t* __restrict__ m1T, const uint16_t* __restrict__ adT,
    const float* __restrict__ b1, const float* __restrict__ adB,
    uint16_t* __restrict__ mlpA)
{
  __shared__ __align__(16) char smem[32768];
  const int tid = threadIdx.x;
  const int m0 = blockIdx.x * 128;
  const int y = blockIdx.y;
  const bool up = (y < 18);
  const int si = m0 >> 13;             // stream of this M-tile
  const int n0 = up ? y * 128 : 0;
  const uint16_t* A = (up ? hb : x2b) + (size_t)m0 * 576;
  const uint16_t* Bt = up ? (m1T + (size_t)n0 * 576) : (adT + (size_t)si * 128 * 576);
  f32x4 acc[4][4] = {};
  gemm_core<128, 576>(A, Bt, smem, tid, acc);

  const int lane = tid & 63, wid = tid >> 6;
  const int wm = (wid >> 1) * 64, wn = (wid & 1) * 64;
  const int r15 = lane & 15, kh = lane >> 4;

  if (up){
#pragma unroll
    for (int i = 0; i < 4; ++i)
#pragma unroll
      for (int tt = 0; tt < 4; ++tt){
        const int gm = m0 + wm + i * 16 + kh * 4 + tt;
#pragma unroll
        for (int j = 0; j < 4; ++j){
          int c = n0 + wn + j * 16 + r15;
          float v = acc[i][j][tt] + b1[c];
          mlpA[(size_t)gm * 2400 + c] = f2bf(geluf(v));
        }
      }
  } else {
    const float* adBp = adB + si * 128;
    float* gl = (float*)smem;   // [128][2] gate logits
#pragma unroll
    for (int i = 0; i < 4; ++i)
#pragma unroll
      for (int j = 0; j < 4; ++j){
        int c = wn + j * 16 + r15;
        if (c == 64 || c == 65){
#pragma unroll
          for (int tt = 0; tt < 4; ++tt){
            int rr2 = wm + i * 16 + kh * 4 + tt;
            gl[rr2 * 2 + (c - 64)] = acc[i][j][tt] + adBp[c];
          }
        }
      }
    __syncthreads();
#pragma unroll
    for (int i = 0; i < 4; ++i)
#pragma unroll
      for (int tt = 0; tt < 4; ++tt){
        int rr2 = wm + i * 16 + kh * 4 + tt;
        int gm = m0 + rr2;
        float l0 = gl[rr2 * 2], l1 = gl[rr2 * 2 + 1];
        float mx = fmaxf(l0, l1);
        float e0 = __expf(l0 - mx), e1 = __expf(l1 - mx);
        float inv = 0.5f / (e0 + e1);
#pragma unroll
        for (int j = 0; j < 4; ++j){
          int c = wn + j * 16 + r15;
          if (c < 96){
            float val;
            if (c < 64){
              float g = ((c >> 5) == 0 ? e0 : e1) * inv;
              val = g * geluf(acc[i][j][tt] + adBp[c]);
            } else if (c == 64) val = e0 * inv;
            else if (c == 65) val = e1 * inv;
            else val = 0.0f;
            mlpA[(size_t)gm * 2400 + 2304 + c] = f2bf(val);
          }
        }
      }
  }
}

// ---------------- BM=128 GEMM: MLP-down + adapter-up + x2 -> out f32 (K=2400, merged M=16384) ----------------
__global__ __launch_bounds__(256) void gemm_addf_k(
    const uint16_t* __restrict__ mlpA, const uint16_t* __restrict__ m2Te, const float* __restrict__ bias,
    const uint16_t* __restrict__ x2b, float* __restrict__ outf)
{
  __shared__ __align__(16) char smem[32768];
  const int tid = threadIdx.x;
  const int m0 = blockIdx.x * 128;
  const int n0 = blockIdx.y * 128;
  const int si = m0 >> 13;
  f32x4 acc[4][4] = {};
  gemm_core<128, 2400>(mlpA + (size_t)m0 * 2400, m2Te + (size_t)si * 640 * 2400 + (size_t)n0 * 2400,
                       smem, tid, acc);

  const int lane = tid & 63, wid = tid >> 6;
  const int wm = (wid >> 1) * 64, wn = (wid & 1) * 64;
  const int r15 = lane & 15, kh = lane >> 4;
  int coln[4]; float bcol[4];
#pragma unroll
  for (int j = 0; j < 4; ++j){
    coln[j] = n0 + wn + j * 16 + r15;
    bcol[j] = (coln[j] < 576) ? bias[coln[j]] : 0.0f;
  }
#pragma unroll
  for (int i = 0; i < 4; ++i)
#pragma unroll
    for (int tt = 0; tt < 4; ++tt){
      const int gm = m0 + wm + i * 16 + kh * 4 + tt;
      const size_t ro = (size_t)gm * 576;
#pragma unroll
      for (int j = 0; j < 4; ++j){
        if (coln[j] < 576){
          float v = acc[i][j][tt] + bcol[j] + bflo(x2b[ro + coln[j]]);
          outf[ro + coln[j]] = v;
        }
      }
    }
}

// ---------------- MFMA windowed attention: 2 waves per (window, head), key-split + combine ----------------
// NOTE: vt pad rows 72..79 hold garbage; MFMA is row-local in the A operand, so garbage only
// lands in output rows d>=72, which the d<72 write guard discards. No pre-zeroing needed.
__global__ __launch_bounds__(128) void attn_mfma_k(
    const uint16_t* __restrict__ qp,   // [8192][576] pooled q (unscaled)
    const uint16_t* __restrict__ kb,   // [32768][576] K
    const uint16_t* __restrict__ vt,   // [1024][80][256] V^T per (window,head)
    uint16_t* __restrict__ o)          // [8192][576]
{
  __shared__ float comb[64][88];       // wave1's m[4], l[4], acco[80]
  const int tid = threadIdx.x;
  const int wave = tid >> 6;
  const int lane = tid & 63;
  const int r15 = lane & 15;
  const int kh = lane >> 4;
  const int bid = blockIdx.x;          // 0..1023
  const int h = bid & 7;
  const int w = bid >> 3;
  const int b = w >> 4;
  const int wy = (w >> 2) & 3;
  const int wx = w & 3;

  const u32x4 ZU = {0, 0, 0, 0};
  const bf16x8 Z8 = __builtin_bit_cast(bf16x8, ZU);
  const float scale = 0.11785113019775793f;  // 1/sqrt(72)

  bf16x8 qf[4][3];
  int qrow[4];
#pragma unroll
  for (int j = 0; j < 4; ++j){
    int q = j * 16 + r15;
    int y = wy * 8 + (q >> 3), x = wx * 8 + (q & 7);
    qrow[j] = b * 1024 + y * 32 + x;
    const uint16_t* qpr = qp + (size_t)qrow[j] * 576 + h * 72;
    qf[j][0] = *(const bf16x8*)(qpr + kh * 8);
    qf[j][1] = *(const bf16x8*)(qpr + 32 + kh * 8);
    qf[j][2] = (kh == 0) ? *(const bf16x8*)(qpr + 64) : Z8;
  }

  float m[4], l[4];
#pragma unroll
  for (int j = 0; j < 4; ++j){ m[j] = -INFINITY; l[j] = 0.0f; }
  f32x4 acco[5][4] = {};
  const size_t vtbase = (size_t)(w * 8 + h) * 80 * 256;

#pragma unroll
  for (int t2 = 0; t2 < 2; ++t2){
    const int t = wave * 2 + t2;       // wave0: tiles 0,1; wave1: tiles 2,3
    f32x4 accs[4][4] = {};
#pragma unroll
    for (int i = 0; i < 4; ++i){
      const uint16_t* kr = kb + (size_t)(b * 4096 + (wy * 16 + t * 4 + i) * 64 + wx * 16 + r15) * 576 + h * 72;
      bf16x8 kf0 = *(const bf16x8*)(kr + kh * 8);
      bf16x8 kf1 = *(const bf16x8*)(kr + 32 + kh * 8);
      bf16x8 kf2 = (kh == 0) ? *(const bf16x8*)(kr + 64) : Z8;
#pragma unroll
      for (int j = 0; j < 4; ++j){
        accs[i][j] = __builtin_amdgcn_mfma_f32_16x16x32_bf16(kf0, qf[j][0], accs[i][j], 0, 0, 0);
        accs[i][j] = __builtin_amdgcn_mfma_f32_16x16x32_bf16(kf1, qf[j][1], accs[i][j], 0, 0, 0);
        accs[i][j] = __builtin_amdgcn_mfma_f32_16x16x32_bf16(kf2, qf[j][2], accs[i][j], 0, 0, 0);
      }
    }
#pragma unroll
    for (int j = 0; j < 4; ++j){
      float mx = -INFINITY;
#pragma unroll
      for (int i = 0; i < 4; ++i)
#pragma unroll
        for (int tt = 0; tt < 4; ++tt){
          float sv = accs[i][j][tt] * scale;
          accs[i][j][tt] = sv;
          mx = fmaxf(mx, sv);
        }
      mx = fmaxf(mx, __shfl_xor(mx, 16));
      mx = fmaxf(mx, __shfl_xor(mx, 32));
      float nm = fmaxf(m[j], mx);
      float f = __expf(m[j] - nm);
      m[j] = nm;
      l[j] *= f;
#pragma unroll
      for (int i2 = 0; i2 < 5; ++i2) acco[i2][j] *= f;
      float ls = 0.0f;
#pragma unroll
      for (int i = 0; i < 4; ++i)
#pragma unroll
        for (int tt = 0; tt < 4; ++tt){
          float p = __expf(accs[i][j][tt] - nm);
          accs[i][j][tt] = p;
          ls += p;
        }
      ls += __shfl_xor(ls, 16);
      ls += __shfl_xor(ls, 32);
      l[j] += ls;
    }
    uint32_t pw[4][4][2];
#pragma unroll
    for (int i = 0; i < 4; ++i)
#pragma unroll
      for (int j = 0; j < 4; ++j){
        pw[i][j][0] = pk2(accs[i][j][0], accs[i][j][1]);
        pw[i][j][1] = pk2(accs[i][j][2], accs[i][j][3]);
      }
#pragma unroll
    for (int ks = 0; ks < 2; ++ks){
      bf16x8 pb[4];
#pragma unroll
      for (int j = 0; j < 4; ++j){
        u32x4 u = {pw[2 * ks][j][0], pw[2 * ks][j][1], pw[2 * ks + 1][j][0], pw[2 * ks + 1][j][1]};
        pb[j] = __builtin_bit_cast(bf16x8, u);
      }
#pragma unroll
      for (int i2 = 0; i2 < 5; ++i2){
        const uint16_t* vr = vt + vtbase + (size_t)(i2 * 16 + r15) * 256 + t * 64 + ks * 32 + kh * 4;
        u32x2 lo = *(const u32x2*)(vr);
        u32x2 hi = *(const u32x2*)(vr + 16);
        u32x4 av = {lo[0], lo[1], hi[0], hi[1]};
        bf16x8 va = __builtin_bit_cast(bf16x8, av);
#pragma unroll
        for (int j = 0; j < 4; ++j)
          acco[i2][j] = __builtin_amdgcn_mfma_f32_16x16x32_bf16(va, pb[j], acco[i2][j], 0, 0, 0);
      }
    }
  }

  // flash-combine the two waves' partials, wave0 writes
  if (wave == 1){
#pragma unroll
    for (int j = 0; j < 4; ++j){ comb[lane][j] = m[j]; comb[lane][4 + j] = l[j]; }
#pragma unroll
    for (int i2 = 0; i2 < 5; ++i2)
#pragma unroll
      for (int j = 0; j < 4; ++j)
#pragma unroll
        for (int tt = 0; tt < 4; ++tt)
          comb[lane][8 + (i2 * 4 + j) * 4 + tt] = acco[i2][j][tt];
  }
  __syncthreads();
  if (wave == 0){
    float fs0[4], fs1[4];
#pragma unroll
    for (int j = 0; j < 4; ++j){
      float m1v = comb[lane][j], l1v = comb[lane][4 + j];
      float nm = fmaxf(m[j], m1v);
      fs0[j] = __expf(m[j] - nm);
      fs1[j] = __expf(m1v - nm);
      l[j] = l[j] * fs0[j] + l1v * fs1[j];
    }
#pragma unroll
    for (int j = 0; j < 4; ++j){
      float inv = 1.0f / l[j];
      uint16_t* orow = o + (size_t)qrow[j] * 576 + h * 72;
#pragma unroll
      for (int i2 = 0; i2 < 5; ++i2)
#pragma unroll
        for (int tt = 0; tt < 4; ++tt){
          int d = i2 * 16 + kh * 4 + tt;
          if (d < 72){
            float ov = acco[i2][j][tt] * fs0[j] + comb[lane][8 + (i2 * 4 + j) * 4 + tt] * fs1[j];
            orow[d] = f2bf(ov * inv);
          }
        }
    }
  }
}

extern "C" void kernel_launch(void* const* d_in, const int* in_sizes, int n_in,
                              void* d_out, int out_size, void* d_ws, size_t ws_size,
                              hipStream_t stream)
{
  (void)in_sizes; (void)n_in; (void)out_size; (void)ws_size;
  const float* srcs[2] = { (const float*)d_in[0], (const float*)d_in[1] };
  const float* n1g    = (const float*)d_in[2];
  const float* n1b    = (const float*)d_in[3];
  const float* proj_w = (const float*)d_in[4];
  const float* proj_b = (const float*)d_in[5];
  const float* qkv_w  = (const float*)d_in[6];
  const float* qkv_b  = (const float*)d_in[7];
  const float* ap_w   = (const float*)d_in[8];
  const float* ap_b   = (const float*)d_in[9];
  const float* n2g    = (const float*)d_in[10];
  const float* n2b    = (const float*)d_in[11];
  const float* w1     = (const float*)d_in[12];
  const float* b1     = (const float*)d_in[13];
  const float* w2     = (const float*)d_in[14];
  const float* b2     = (const float*)d_in[15];
  const float* gw     = (const float*)d_in[16];
  const float* gb     = (const float*)d_in[17];
  const float* dwn    = (const float*)d_in[18];
  const float* dbn    = (const float*)d_in[19];
  const float* uw     = (const float*)d_in[20];
  const float* ub     = (const float*)d_in[21];

  char* ws = (char*)d_ws;
  size_t off = 0;
  auto alloc = [&](size_t bytes){ size_t o = off; off += (bytes + 255) & ~(size_t)255; return o; };

  // shared weights (bf16) — ~11.2 MB
  uint16_t* pqT   = (uint16_t*)(ws + alloc((size_t)1152 * 288 * 2));  // [proj 576 | q 576]
  float*    pqB   = (float*)(ws + alloc((size_t)1152 * 4));
  uint16_t* kvT   = (uint16_t*)(ws + alloc((size_t)1152 * 288 * 2));
  uint16_t* aT    = (uint16_t*)(ws + alloc((size_t)640 * 576 * 2));
  uint16_t* m1T   = (uint16_t*)(ws + alloc((size_t)2304 * 576 * 2));
  uint16_t* m2Te  = (uint16_t*)(ws + alloc((size_t)2 * 640 * 2400 * 2));
  uint16_t* adT   = (uint16_t*)(ws + alloc((size_t)2 * 128 * 576 * 2));
  float*    adB   = (float*)(ws + alloc((size_t)2 * 128 * 4));
  // activations (total ws ~203 MB)
  uint16_t* xn   = (uint16_t*)(ws + alloc((size_t)32768 * 288 * 2));   // per-stream reuse
  uint16_t* sc2  = (uint16_t*)(ws + alloc((size_t)16384 * 576 * 2));   // both streams
  size_t oQP = alloc((size_t)16384 * 576 * 2);       // qp halves; later x2b merged
  uint16_t* qp2  = (uint16_t*)(ws + oQP);
  uint16_t* x2b  = (uint16_t*)(ws + oQP);
  uint16_t* kb   = (uint16_t*)(ws + alloc((size_t)32768 * 576 * 2));   // per-stream reuse
  size_t oVT = alloc((size_t)16384 * 2400 * 2);      // vt (41.9MB, reuse) ; later mlpA [16384][2400]
  uint16_t* vt   = (uint16_t*)(ws + oVT);
  uint16_t* mlpA = (uint16_t*)(ws + oVT);
  size_t oOB = alloc((size_t)16384 * 576 * 2);       // ob both streams; later hb merged
  uint16_t* ob2  = (uint16_t*)(ws + oOB);
  uint16_t* hb2  = (uint16_t*)(ws + oOB);

  // weight prep (once)
  wtrans_k<<<(576 * 288 + 255) / 256, 256, 0, stream>>>(proj_w, pqT, 288, 576, 576, 576, 0);
  wtrans_k<<<(576 * 288 + 255) / 256, 256, 0, stream>>>(qkv_w, pqT + (size_t)576 * 288, 288, 576, 576, 1728, 0);
  mk_pqb_k<<<5, 256, 0, stream>>>(proj_b, qkv_b, pqB);
  wtrans_k<<<(1152 * 288 + 255) / 256, 256, 0, stream>>>(qkv_w, kvT, 288, 1152, 1152, 1728, 576);
  wtrans_k<<<(640 * 576 + 255) / 256, 256, 0, stream>>>(ap_w, aT, 576, 576, 640, 576, 0);
  wtrans_k<<<(2304 * 576 + 255) / 256, 256, 0, stream>>>(w1, m1T, 576, 2304, 2304, 2304, 0);
  mk_m2te_k<<<(2 * 640 * 2400 + 255) / 256, 256, 0, stream>>>(w2, uw, ub, m2Te);
  mk_adt_k<<<(2 * 128 * 576 + 255) / 256, 256, 0, stream>>>(dwn, gw, dbn, gb, adT, adB);

  // -------- frontend per stream --------
  for (int si = 0; si < 2; ++si){
    const size_t half = (size_t)si * 8192 * 576;

    // LN1 -> xn bf16 [32768 x 288]
    ln_k<float><<<8192, 256, 0, stream>>>(srcs[si], 288, n1g, n1b, xn);

    // merged pool(proj+q) + kv GEMM (2-buf BM=128 core) -> sc, qp, kb, vt
    gemm_pkv_k<<<dim3(256, 18), 256, 0, stream>>>(xn, pqT, kvT, pqB, qkv_b + 576,
                                                  sc2 + half, qp2 + half, kb, vt);

    // MFMA windowed attention (2-wave key-split) -> ob bf16
    attn_mfma_k<<<1024, 128, 0, stream>>>(qp2 + half, kb, vt, ob2 + half);
  }

  // -------- backend merged over both streams (M=16384, BM=128) --------
  // attn out-proj + shortcut -> x2b bf16 (aliases qp2, dead after attn)
  gemm_add1_k<<<dim3(128, 5), 256, 0, stream>>>(ob2, aT, ap_b, sc2, x2b);

  // LN2 -> hb bf16 (aliases ob2, dead after add1)
  ln_k<uint16_t><<<4096, 256, 0, stream>>>(x2b, 576, n2g, n2b, hb2);

  // MLP up + gelu (cols 0..2303) + adapter phase-1 (cols 2304..2399) -> mlpA (aliases vt)
  gemm_upad_k<<<dim3(128, 19), 256, 0, stream>>>(hb2, x2b, m1T, adT, b1, adB, mlpA);

  // MLP down + adapter up + x2 -> out f32 (K=2400 extended)
  gemm_addf_k<<<dim3(128, 5), 256, 0, stream>>>(mlpA, m2Te, b2, x2b, (float*)d_out);
}

// Round 14
// 550.126 us; speedup vs baseline: 1.1092x; 1.0138x over previous
//
#include <hip/hip_runtime.h>
#include <cstdint>
#include <math.h>
#include <type_traits>

typedef __bf16 bf16_t;
typedef __bf16 bf16x8 __attribute__((ext_vector_type(8)));
typedef float f32x4 __attribute__((ext_vector_type(4)));
typedef uint32_t u32x4 __attribute__((ext_vector_type(4)));
typedef uint32_t u32x2 __attribute__((ext_vector_type(2)));

#define DI __device__ __forceinline__

DI float bflo(uint32_t u){ return __builtin_bit_cast(float, (uint32_t)(u << 16)); }
DI float bfhi(uint32_t u){ return __builtin_bit_cast(float, (uint32_t)(u & 0xffff0000u)); }
DI uint16_t f2bf(float f){ bf16_t h = (bf16_t)f; return __builtin_bit_cast(uint16_t, h); }
DI uint32_t pk2(float a, float b){ return (uint32_t)f2bf(a) | ((uint32_t)f2bf(b) << 16); }
// gelu(tanh-approx) == x * sigmoid(2u): HW exp+rcp instead of libm tanhf.
DI float geluf(float x){
  float t = x * x;
  float p = fmaf(t, 0.0356774081f, 0.7978845608f);
  float e = __expf(-2.0f * x * p);
  return x * __builtin_amdgcn_rcpf(1.0f + e);
}

#if defined(__has_builtin)
#if __has_builtin(__builtin_amdgcn_global_load_lds)
#define USE_GLLDS 1
#endif
#endif

#if USE_GLLDS
DI void gload_lds16(const void* g, void* l){
  __builtin_amdgcn_global_load_lds((__attribute__((address_space(1))) void*)g,
                                   (__attribute__((address_space(3))) void*)l, 16, 0, 0);
}
#endif

// ---------------- segmented weight prep: 6 jobs in one launch ----------------
// y=0: proj_w -> pqT[0];       y=1: qkv_w q-cols -> pqT[576*288]
// y=2: qkv_w kv-cols -> kvT;   y=3: ap_w -> aT (Np=640)
// y=4: w1 -> m1T;              y=5: pqB bias concat
__global__ __launch_bounds__(256) void wprep_k(
    const float* __restrict__ proj_w, const float* __restrict__ qkv_w,
    const float* __restrict__ ap_w, const float* __restrict__ w1,
    const float* __restrict__ proj_b, const float* __restrict__ qkv_b,
    uint16_t* __restrict__ pqT, uint16_t* __restrict__ kvT,
    uint16_t* __restrict__ aT, uint16_t* __restrict__ m1T, float* __restrict__ pqB)
{
  const int y = blockIdx.y;
  const int idx = blockIdx.x * 256 + threadIdx.x;
  if (y == 5){
    if (idx < 1152) pqB[idx] = (idx < 576) ? proj_b[idx] : qkv_b[idx - 576];
    return;
  }
  const float* W; uint16_t* Wt; int K, N, Np, ldw, c0;
  switch (y){
    case 0: W = proj_w; Wt = pqT;                      K = 288; N = 576;  Np = 576;  ldw = 576;  c0 = 0;   break;
    case 1: W = qkv_w;  Wt = pqT + (size_t)576 * 288;  K = 288; N = 576;  Np = 576;  ldw = 1728; c0 = 0;   break;
    case 2: W = qkv_w;  Wt = kvT;                      K = 288; N = 1152; Np = 1152; ldw = 1728; c0 = 576; break;
    case 3: W = ap_w;   Wt = aT;                       K = 576; N = 576;  Np = 640;  ldw = 576;  c0 = 0;   break;
    default:W = w1;     Wt = m1T;                      K = 576; N = 2304; Np = 2304; ldw = 2304; c0 = 0;   break;
  }
  if (idx >= Np * K) return;
  int n = idx / K, k = idx - n * K;
  float v = (n < N) ? W[(size_t)k * ldw + c0 + n] : 0.0f;
  Wt[idx] = f2bf(v);
}

// ---------------- build extended MLP-down weight: m2Te[si][640][2400] ----------------
__global__ __launch_bounds__(256) void mk_m2te_k(const float* __restrict__ w2,
    const float* __restrict__ uw, const float* __restrict__ ub, uint16_t* __restrict__ m2Te)
{
  int idx = blockIdx.x * 256 + threadIdx.x;
  if (idx >= 2 * 640 * 2400) return;
  int si = idx / (640 * 2400);
  int rem = idx - si * 640 * 2400;
  int n = rem / 2400, k = rem - n * 2400;
  float v = 0.0f;
  if (n < 576){
    if (k < 2304) v = w2[(size_t)k * 576 + n];
    else if (k < 2368){
      int e = (k - 2304) >> 5, r = (k - 2304) & 31;
      v = uw[((size_t)(si * 2 + e) * 32 + r) * 576 + n];
    } else if (k < 2370){
      v = ub[(size_t)(si * 2 + (k - 2368)) * 576 + n];
    }
  }
  m2Te[idx] = f2bf(v);
}

// ---------------- build adapter phase-1 weight adT[si][128][576] + bias adB[si][128] ----------------
__global__ __launch_bounds__(256) void mk_adt_k(const float* __restrict__ dwn, const float* __restrict__ gw,
    const float* __restrict__ dbn, const float* __restrict__ gb,
    uint16_t* __restrict__ adT, float* __restrict__ adB)
{
  int idx = blockIdx.x * 256 + threadIdx.x;
  if (idx >= 2 * 128 * 576) return;
  int si = idx / (128 * 576);
  int rem = idx - si * 128 * 576;
  int n = rem / 576, k = rem - n * 576;
  float v = 0.0f;
  if (n < 64){
    int e = n >> 5, r = n & 31;
    v = dwn[((size_t)(si * 2 + e) * 576 + k) * 32 + r];
  } else if (n < 66){
    v = gw[(size_t)si * 1152 + k * 2 + (n - 64)];
  }
  adT[idx] = f2bf(v);
  if (k == 0){
    float bv = 0.0f;
    if (n < 64) bv = dbn[si * 64 + (n >> 5) * 32 + (n & 31)];
    else if (n < 66) bv = gb[si * 2 + (n - 64)];
    adB[si * 128 + n] = bv;
  }
}

// ---------------- LayerNorm (wave per token) -> bf16; two-source (A then B rows) ----------------
template<typename TIN>
__global__ __launch_bounds__(256) void ln_k(const TIN* __restrict__ inA, const TIN* __restrict__ inB,
                                            const int rowsA, const int D,
                                            const float* __restrict__ g, const float* __restrict__ bb,
                                            uint16_t* __restrict__ outp)
{
  const int token = blockIdx.x * 4 + (threadIdx.x >> 6);
  const int lane = threadIdx.x & 63;
  const TIN* in = (token < rowsA) ? (inA + (size_t)token * D) : (inB + (size_t)(token - rowsA) * D);
  const int nf4 = D >> 2;
  f32x4 v[3];
  float s = 0.f, sq = 0.f;
#pragma unroll
  for (int i = 0; i < 3; ++i){
    const int c = lane + 64 * i;
    if (c < nf4){
      if constexpr (std::is_same<TIN, float>::value){
        v[i] = *(const f32x4*)(in + 4 * c);
      } else {
        u32x2 u = *(const u32x2*)((const uint16_t*)in + 4 * c);
        v[i][0] = bflo(u[0]); v[i][1] = bfhi(u[0]);
        v[i][2] = bflo(u[1]); v[i][3] = bfhi(u[1]);
      }
#pragma unroll
      for (int e = 0; e < 4; ++e){ s += v[i][e]; sq += v[i][e] * v[i][e]; }
    }
  }
#pragma unroll
  for (int off = 32; off; off >>= 1){
    s  += __shfl_xor(s, off);
    sq += __shfl_xor(sq, off);
  }
  const float mean = s / (float)D;
  const float var = sq / (float)D - mean * mean;
  const float inv = rsqrtf(var + 1e-6f);
  uint16_t* orow = outp + (size_t)token * D;
#pragma unroll
  for (int i = 0; i < 3; ++i){
    const int c = lane + 64 * i;
    if (c < nf4){
      float f0 = (v[i][0] - mean) * inv * g[4*c+0] + bb[4*c+0];
      float f1 = (v[i][1] - mean) * inv * g[4*c+1] + bb[4*c+1];
      float f2 = (v[i][2] - mean) * inv * g[4*c+2] + bb[4*c+2];
      float f3 = (v[i][3] - mean) * inv * g[4*c+3] + bb[4*c+3];
      u32x2 pk; pk[0] = pk2(f0, f1); pk[1] = pk2(f2, f3);
      *(u32x2*)(orow + 4 * c) = pk;
    }
  }
}

// ---------------- shared GEMM core: BMx128 tile, 2-buf __syncthreads, compile-time K ----------------
template<int BM, int KK>
DI void gemm_core(const uint16_t* __restrict__ A, const uint16_t* __restrict__ Bt,
                  char* smem, const int tid, f32x4 (*acc)[4])
{
  constexpr int MI = BM / 32;
  constexpr int ABUF = BM * 64;        // A bytes per buffer
  constexpr int nt = KK >> 5;
  char* A0 = smem;
  char* A1 = smem + ABUF;
  char* B0 = smem + 2 * ABUF;
  char* B1 = smem + 2 * ABUF + 8192;
  const int lane = tid & 63;
  const int wid = tid >> 6;
  const int wm = (wid >> 1) * (BM / 2);
  const int wn = (wid & 1) * 64;
  const int r15 = lane & 15, kh = lane >> 4;
  const int rA0 = tid >> 2, c16 = tid & 3;
  const int kS = ((c16 ^ ((rA0 >> 1) & 3)) << 3);   // pre-swizzled k-offset (elements)

  auto stage = [&](char* Ad, char* Bd, int t){
    const uint16_t* ga0 = A + (size_t)rA0 * KK + t * 32 + kS;
    const uint16_t* gb0 = Bt + (size_t)rA0 * KK + t * 32 + kS;
    const uint16_t* gb1 = Bt + (size_t)(rA0 + 64) * KK + t * 32 + kS;
#if USE_GLLDS
    gload_lds16(ga0, Ad + tid * 16);
    gload_lds16(gb0, Bd + tid * 16);
    gload_lds16(gb1, Bd + tid * 16 + 4096);
    if constexpr (BM == 128){
      const uint16_t* ga1 = A + (size_t)(rA0 + 64) * KK + t * 32 + kS;
      gload_lds16(ga1, Ad + tid * 16 + 4096);
    }
#else
    *(u32x4*)(Ad + tid * 16)        = *(const u32x4*)ga0;
    *(u32x4*)(Bd + tid * 16)        = *(const u32x4*)gb0;
    *(u32x4*)(Bd + tid * 16 + 4096) = *(const u32x4*)gb1;
    if constexpr (BM == 128){
      const uint16_t* ga1 = A + (size_t)(rA0 + 64) * KK + t * 32 + kS;
      *(u32x4*)(Ad + tid * 16 + 4096) = *(const u32x4*)ga1;
    }
#endif
  };

  stage(A0, B0, 0);
  __syncthreads();
  for (int t = 0; t < nt; ++t){
    char* Ac = (t & 1) ? A1 : A0;
    char* Bc = (t & 1) ? B1 : B0;
    if (t + 1 < nt) stage((t & 1) ? A0 : A1, (t & 1) ? B0 : B1, t + 1);
    bf16x8 af[MI], bfv[4];
#pragma unroll
    for (int i = 0; i < MI; ++i){
      int rowA = wm + i * 16 + r15;
      af[i] = *(const bf16x8*)(Ac + rowA * 64 + ((kh ^ ((rowA >> 1) & 3)) << 4));
    }
#pragma unroll
    for (int j = 0; j < 4; ++j){
      int rowB = wn + j * 16 + r15;
      bfv[j] = *(const bf16x8*)(Bc + rowB * 64 + ((kh ^ ((rowB >> 1) & 3)) << 4));
    }
#pragma unroll
    for (int i = 0; i < MI; ++i)
#pragma unroll
      for (int j = 0; j < 4; ++j)
        acc[i][j] = __builtin_amdgcn_mfma_f32_16x16x32_bf16(af[i], bfv[j], acc[i][j], 0, 0, 0);
    __syncthreads();
  }
}

// ---------------- merged pool(proj+q)+kv GEMM over A=xn slice, M=32768, K=288 ----------------
__global__ __launch_bounds__(256) void gemm_pkv_k(
    const uint16_t* __restrict__ xn, const uint16_t* __restrict__ pqT, const uint16_t* __restrict__ kvT,
    const float* __restrict__ pqB, const float* __restrict__ kvB,
    uint16_t* __restrict__ sc, uint16_t* __restrict__ qp,
    uint16_t* __restrict__ kb, uint16_t* __restrict__ vt)
{
  __shared__ __align__(16) char smem[34816];   // gemm core 32KB; pool epilogue Cp 128x136x2
  const int tid = threadIdx.x;
  const int m0 = blockIdx.x * 128;
  const int y = blockIdx.y;            // 0..17
  const bool pool = (y < 9);
  const int n0 = pool ? y * 128 : (y - 9) * 128;
  const uint16_t* Bt = (pool ? pqT : kvT) + (size_t)n0 * 288;
  f32x4 acc[4][4] = {};
  gemm_core<128, 288>(xn + (size_t)m0 * 288, Bt, smem, tid, acc);

  const int lane = tid & 63, wid = tid >> 6;
  const int wm = (wid >> 1) * 64, wn = (wid & 1) * 64;
  const int r15 = lane & 15, kh = lane >> 4;

  if (pool){
    uint16_t* Cp = (uint16_t*)smem;    // stride 136 breaks the 8-way write aliasing
#pragma unroll
    for (int i = 0; i < 4; ++i)
#pragma unroll
      for (int j = 0; j < 4; ++j)
#pragma unroll
        for (int tt = 0; tt < 4; ++tt){
          int rr2 = wm + i * 16 + kh * 4 + tt;
          int cc = wn + j * 16 + r15;
          Cp[rr2 * 136 + cc] = f2bf(acc[i][j][tt]);
        }
    __syncthreads();
    const int orow0 = m0 >> 2;
#pragma unroll
    for (int e2 = 0; e2 < 16; ++e2){
      int idx = tid + 256 * e2;
      int X = idx >> 7, c = idx & 127;
      int gn = n0 + c;
      float v0 = bflo(Cp[(2 * X) * 136 + c]);
      float v1 = bflo(Cp[(2 * X + 1) * 136 + c]);
      float v2 = bflo(Cp[(64 + 2 * X) * 136 + c]);
      float v3 = bflo(Cp[(65 + 2 * X) * 136 + c]);
      float v = fmaxf(fmaxf(v0, v1), fmaxf(v2, v3)) + pqB[gn];
      if (gn < 576)
        sc[(size_t)(orow0 + X) * 576 + gn] = f2bf(v);
      else
        qp[(size_t)(orow0 + X) * 576 + (gn - 576)] = f2bf(v);
    }
  } else {
    int coln[4]; float bcol[4];
#pragma unroll
    for (int j = 0; j < 4; ++j){
      coln[j] = n0 + wn + j * 16 + r15;
      bcol[j] = kvB[coln[j]];
    }
#pragma unroll
    for (int i = 0; i < 4; ++i)
#pragma unroll
      for (int tt = 0; tt < 4; ++tt){
        const int gm = m0 + wm + i * 16 + kh * 4 + tt;
#pragma unroll
        for (int j = 0; j < 4; ++j){
          float v = acc[i][j][tt] + bcol[j];
          int n = coln[j];
          if (n < 576){
            kb[(size_t)gm * 576 + n] = f2bf(v);
          } else {
            int d = n - 576;
            int hh = d / 72, dd = d - hh * 72;
            int bimg = gm >> 12, yy = (gm >> 6) & 63, xx = gm & 63;
            int w = bimg * 16 + (yy >> 4) * 4 + (xx >> 4);
            int kl = (yy & 15) * 16 + (xx & 15);
            vt[((size_t)(w * 8 + hh) * 80 + dd) * 256 + kl] = f2bf(v);
          }
        }
      }
  }
}

// ---------------- BM=128 GEMM: attn-proj + shortcut -> x2b bf16 (merged M=16384) ----------------
__global__ __launch_bounds__(256) void gemm_add1_k(
    const uint16_t* __restrict__ ob, const uint16_t* __restrict__ aT, const float* __restrict__ bias,
    const uint16_t* __restrict__ sc, uint16_t* __restrict__ x2b)
{
  __shared__ __align__(16) char smem[32768];
  const int tid = threadIdx.x;
  const int m0 = blockIdx.x * 128;
  const int n0 = blockIdx.y * 128;
  f32x4 acc[4][4] = {};
  gemm_core<128, 576>(ob + (size_t)m0 * 576, aT + (size_t)n0 * 576, smem, tid, acc);

  const int lane = tid & 63, wid = tid >> 6;
  const int wm = (wid >> 1) * 64, wn = (wid & 1) * 64;
  const int r15 = lane & 15, kh = lane >> 4;
  int coln[4]; float bcol[4];
#pragma unroll
  for (int j = 0; j < 4; ++j){
    coln[j] = n0 + wn + j * 16 + r15;
    bcol[j] = (coln[j] < 576) ? bias[coln[j]] : 0.0f;
  }
#pragma unroll
  for (int i = 0; i < 4; ++i)
#pragma unroll
    for (int tt = 0; tt < 4; ++tt){
      const int gm = m0 + wm + i * 16 + kh * 4 + tt;
      const size_t ro = (size_t)gm * 576;
#pragma unroll
      for (int j = 0; j < 4; ++j){
        if (coln[j] < 576){
          float v = acc[i][j][tt] + bcol[j] + bflo(sc[ro + coln[j]]);
          x2b[ro + coln[j]] = f2bf(v);
        }
      }
    }
}

// ---------------- BM=128 merged GEMM: MLP-up(gelu) + adapter phase-1, K=576 (merged M=16384) ----------------
__global__ __launch_bounds__(256) void gemm_upad_k(
    const uint16_t* __restrict__ hb, const uint16_t* __restrict__ x2b,
    const uint16_t* __restrict__ m1T, const uint16_t* __restrict__ adT,
    const float* __restrict__ b1, const float* __restrict__ adB,
    uint16_t* __restrict__ mlpA)
{
  __shared__ __align__(16) char smem[32768];
  const int tid = threadIdx.x;
  const int m0 = blockIdx.x * 128;
  const int y = blockIdx.y;
  const bool up = (y < 18);
  const int si = m0 >> 13;             // stream of this M-tile
  const int n0 = up ? y * 128 : 0;
  const uint16_t* A = (up ? hb : x2b) + (size_t)m0 * 576;
  const uint16_t* Bt = up ? (m1T + (size_t)n0 * 576) : (adT + (size_t)si * 128 * 576);
  f32x4 acc[4][4] = {};
  gemm_core<128, 576>(A, Bt, smem, tid, acc);

  const int lane = tid & 63, wid = tid >> 6;
  const int wm = (wid >> 1) * 64, wn = (wid & 1) * 64;
  const int r15 = lane & 15, kh = lane >> 4;

  if (up){
#pragma unroll
    for (int i = 0; i < 4; ++i)
#pragma unroll
      for (int tt = 0; tt < 4; ++tt){
        const int gm = m0 + wm + i * 16 + kh * 4 + tt;
#pragma unroll
        for (int j = 0; j < 4; ++j){
          int c = n0 + wn + j * 16 + r15;
          float v = acc[i][j][tt] + b1[c];
          mlpA[(size_t)gm * 2400 + c] = f2bf(geluf(v));
        }
      }
  } else {
    const float* adBp = adB + si * 128;
    float* gl = (float*)smem;   // [128][2] gate logits
#pragma unroll
    for (int i = 0; i < 4; ++i)
#pragma unroll
      for (int j = 0; j < 4; ++j){
        int c = wn + j * 16 + r15;
        if (c == 64 || c == 65){
#pragma unroll
          for (int tt = 0; tt < 4; ++tt){
            int rr2 = wm + i * 16 + kh * 4 + tt;
            gl[rr2 * 2 + (c - 64)] = acc[i][j][tt] + adBp[c];
          }
        }
      }
    __syncthreads();
#pragma unroll
    for (int i = 0; i < 4; ++i)
#pragma unroll
      for (int tt = 0; tt < 4; ++tt){
        int rr2 = wm + i * 16 + kh * 4 + tt;
        int gm = m0 + rr2;
        float l0 = gl[rr2 * 2], l1 = gl[rr2 * 2 + 1];
        float mx = fmaxf(l0, l1);
        float e0 = __expf(l0 - mx), e1 = __expf(l1 - mx);
        float inv = 0.5f / (e0 + e1);
#pragma unroll
        for (int j = 0; j < 4; ++j){
          int c = wn + j * 16 + r15;
          if (c < 96){
            float val;
            if (c < 64){
              float g = ((c >> 5) == 0 ? e0 : e1) * inv;
              val = g * geluf(acc[i][j][tt] + adBp[c]);
            } else if (c == 64) val = e0 * inv;
            else if (c == 65) val = e1 * inv;
            else val = 0.0f;
            mlpA[(size_t)gm * 2400 + 2304 + c] = f2bf(val);
          }
        }
      }
  }
}

// ---------------- BM=128 GEMM: MLP-down + adapter-up + x2 -> out f32 (K=2400, merged M=16384) ----------------
__global__ __launch_bounds__(256) void gemm_addf_k(
    const uint16_t* __restrict__ mlpA, const uint16_t* __restrict__ m2Te, const float* __restrict__ bias,
    const uint16_t* __restrict__ x2b, float* __restrict__ outf)
{
  __shared__ __align__(16) char smem[32768];
  const int tid = threadIdx.x;
  const int m0 = blockIdx.x * 128;
  const int n0 = blockIdx.y * 128;
  const int si = m0 >> 13;
  f32x4 acc[4][4] = {};
  gemm_core<128, 2400>(mlpA + (size_t)m0 * 2400, m2Te + (size_t)si * 640 * 2400 + (size_t)n0 * 2400,
                       smem, tid, acc);

  const int lane = tid & 63, wid = tid >> 6;
  const int wm = (wid >> 1) * 64, wn = (wid & 1) * 64;
  const int r15 = lane & 15, kh = lane >> 4;
  int coln[4]; float bcol[4];
#pragma unroll
  for (int j = 0; j < 4; ++j){
    coln[j] = n0 + wn + j * 16 + r15;
    bcol[j] = (coln[j] < 576) ? bias[coln[j]] : 0.0f;
  }
#pragma unroll
  for (int i = 0; i < 4; ++i)
#pragma unroll
    for (int tt = 0; tt < 4; ++tt){
      const int gm = m0 + wm + i * 16 + kh * 4 + tt;
      const size_t ro = (size_t)gm * 576;
#pragma unroll
      for (int j = 0; j < 4; ++j){
        if (coln[j] < 576){
          float v = acc[i][j][tt] + bcol[j] + bflo(x2b[ro + coln[j]]);
          outf[ro + coln[j]] = v;
        }
      }
    }
}

// ---------------- MFMA windowed attention: 2 waves per (window, head), key-split + combine ----------------
// vt pad rows 72..79 hold garbage; MFMA is row-local in A, so garbage only lands in output
// rows d>=72, which the packed-store guard (d0<72) discards. No pre-zeroing needed.
__global__ __launch_bounds__(128) void attn_mfma_k(
    const uint16_t* __restrict__ qp,   // [8192][576] pooled q (unscaled)
    const uint16_t* __restrict__ kb,   // [32768][576] K
    const uint16_t* __restrict__ vt,   // [1024][80][256] V^T per (window,head)
    uint16_t* __restrict__ o)          // [8192][576]
{
  __shared__ float comb[64][88];       // wave1's m[4], l[4], acco[80]
  const int tid = threadIdx.x;
  const int wave = tid >> 6;
  const int lane = tid & 63;
  const int r15 = lane & 15;
  const int kh = lane >> 4;
  const int bid = blockIdx.x;          // 0..1023
  const int h = bid & 7;
  const int w = bid >> 3;
  const int b = w >> 4;
  const int wy = (w >> 2) & 3;
  const int wx = w & 3;

  const u32x4 ZU = {0, 0, 0, 0};
  const bf16x8 Z8 = __builtin_bit_cast(bf16x8, ZU);
  const float scale = 0.11785113019775793f;  // 1/sqrt(72)

  bf16x8 qf[4][3];
  int qrow[4];
#pragma unroll
  for (int j = 0; j < 4; ++j){
    int q = j * 16 + r15;
    int y = wy * 8 + (q >> 3), x = wx * 8 + (q & 7);
    qrow[j] = b * 1024 + y * 32 + x;
    const uint16_t* qpr = qp + (size_t)qrow[j] * 576 + h * 72;
    qf[j][0] = *(const bf16x8*)(qpr + kh * 8);
    qf[j][1] = *(const bf16x8*)(qpr + 32 + kh * 8);
    qf[j][2] = (kh == 0) ? *(const bf16x8*)(qpr + 64) : Z8;
  }

  float m[4], l[4];
#pragma unroll
  for (int j = 0; j < 4; ++j){ m[j] = -INFINITY; l[j] = 0.0f; }
  f32x4 acco[5][4] = {};
  const size_t vtbase = (size_t)(w * 8 + h) * 80 * 256;

#pragma unroll
  for (int t2 = 0; t2 < 2; ++t2){
    const int t = wave * 2 + t2;       // wave0: tiles 0,1; wave1: tiles 2,3
    f32x4 accs[4][4] = {};
#pragma unroll
    for (int i = 0; i < 4; ++i){
      const uint16_t* kr = kb + (size_t)(b * 4096 + (wy * 16 + t * 4 + i) * 64 + wx * 16 + r15) * 576 + h * 72;
      bf16x8 kf0 = *(const bf16x8*)(kr + kh * 8);
      bf16x8 kf1 = *(const bf16x8*)(kr + 32 + kh * 8);
      bf16x8 kf2 = (kh == 0) ? *(const bf16x8*)(kr + 64) : Z8;
#pragma unroll
      for (int j = 0; j < 4; ++j){
        accs[i][j] = __builtin_amdgcn_mfma_f32_16x16x32_bf16(kf0, qf[j][0], accs[i][j], 0, 0, 0);
        accs[i][j] = __builtin_amdgcn_mfma_f32_16x16x32_bf16(kf1, qf[j][1], accs[i][j], 0, 0, 0);
        accs[i][j] = __builtin_amdgcn_mfma_f32_16x16x32_bf16(kf2, qf[j][2], accs[i][j], 0, 0, 0);
      }
    }
#pragma unroll
    for (int j = 0; j < 4; ++j){
      float mx = -INFINITY;
#pragma unroll
      for (int i = 0; i < 4; ++i)
#pragma unroll
        for (int tt = 0; tt < 4; ++tt){
          float sv = accs[i][j][tt] * scale;
          accs[i][j][tt] = sv;
          mx = fmaxf(mx, sv);
        }
      mx = fmaxf(mx, __shfl_xor(mx, 16));
      mx = fmaxf(mx, __shfl_xor(mx, 32));
      float nm = fmaxf(m[j], mx);
      float f = __expf(m[j] - nm);
      m[j] = nm;
      l[j] *= f;
#pragma unroll
      for (int i2 = 0; i2 < 5; ++i2) acco[i2][j] *= f;
      float ls = 0.0f;
#pragma unroll
      for (int i = 0; i < 4; ++i)
#pragma unroll
        for (int tt = 0; tt < 4; ++tt){
          float p = __expf(accs[i][j][tt] - nm);
          accs[i][j][tt] = p;
          ls += p;
        }
      ls += __shfl_xor(ls, 16);
      ls += __shfl_xor(ls, 32);
      l[j] += ls;
    }
    uint32_t pw[4][4][2];
#pragma unroll
    for (int i = 0; i < 4; ++i)
#pragma unroll
      for (int j = 0; j < 4; ++j){
        pw[i][j][0] = pk2(accs[i][j][0], accs[i][j][1]);
        pw[i][j][1] = pk2(accs[i][j][2], accs[i][j][3]);
      }
#pragma unroll
    for (int ks = 0; ks < 2; ++ks){
      bf16x8 pb[4];
#pragma unroll
      for (int j = 0; j < 4; ++j){
        u32x4 u = {pw[2 * ks][j][0], pw[2 * ks][j][1], pw[2 * ks + 1][j][0], pw[2 * ks + 1][j][1]};
        pb[j] = __builtin_bit_cast(bf16x8, u);
      }
#pragma unroll
      for (int i2 = 0; i2 < 5; ++i2){
        const uint16_t* vr = vt + vtbase + (size_t)(i2 * 16 + r15) * 256 + t * 64 + ks * 32 + kh * 4;
        u32x2 lo = *(const u32x2*)(vr);
        u32x2 hi = *(const u32x2*)(vr + 16);
        u32x4 av = {lo[0], lo[1], hi[0], hi[1]};
        bf16x8 va = __builtin_bit_cast(bf16x8, av);
#pragma unroll
        for (int j = 0; j < 4; ++j)
          acco[i2][j] = __builtin_amdgcn_mfma_f32_16x16x32_bf16(va, pb[j], acco[i2][j], 0, 0, 0);
      }
    }
  }

  // flash-combine the two waves' partials, wave0 writes (packed 8B stores)
  if (wave == 1){
#pragma unroll
    for (int j = 0; j < 4; ++j){ comb[lane][j] = m[j]; comb[lane][4 + j] = l[j]; }
#pragma unroll
    for (int i2 = 0; i2 < 5; ++i2)
#pragma unroll
      for (int j = 0; j < 4; ++j)
#pragma unroll
        for (int tt = 0; tt < 4; ++tt)
          comb[lane][8 + (i2 * 4 + j) * 4 + tt] = acco[i2][j][tt];
  }
  __syncthreads();
  if (wave == 0){
    float fs0[4], fs1[4];
#pragma unroll
    for (int j = 0; j < 4; ++j){
      float m1v = comb[lane][j], l1v = comb[lane][4 + j];
      float nm = fmaxf(m[j], m1v);
      fs0[j] = __expf(m[j] - nm);
      fs1[j] = __expf(m1v - nm);
      l[j] = l[j] * fs0[j] + l1v * fs1[j];
    }
#pragma unroll
    for (int j = 0; j < 4; ++j){
      float inv = 1.0f / l[j];
      uint16_t* orow = o + (size_t)qrow[j] * 576 + h * 72;
#pragma unroll
      for (int i2 = 0; i2 < 5; ++i2){
        const int d0 = i2 * 16 + kh * 4;
        if (d0 < 72){
          float ov[4];
#pragma unroll
          for (int tt = 0; tt < 4; ++tt)
            ov[tt] = (acco[i2][j][tt] * fs0[j] + comb[lane][8 + (i2 * 4 + j) * 4 + tt] * fs1[j]) * inv;
          u32x2 pk; pk[0] = pk2(ov[0], ov[1]); pk[1] = pk2(ov[2], ov[3]);
          *(u32x2*)(orow + d0) = pk;   // 8B-aligned: 1152|144h|2*d0 all multiples of 8
        }
      }
    }
  }
}

extern "C" void kernel_launch(void* const* d_in, const int* in_sizes, int n_in,
                              void* d_out, int out_size, void* d_ws, size_t ws_size,
                              hipStream_t stream)
{
  (void)in_sizes; (void)n_in; (void)out_size; (void)ws_size;
  const float* rgb    = (const float*)d_in[0];
  const float* depth  = (const float*)d_in[1];
  const float* n1g    = (const float*)d_in[2];
  const float* n1b    = (const float*)d_in[3];
  const float* proj_w = (const float*)d_in[4];
  const float* proj_b = (const float*)d_in[5];
  const float* qkv_w  = (const float*)d_in[6];
  const float* qkv_b  = (const float*)d_in[7];
  const float* ap_w   = (const float*)d_in[8];
  const float* ap_b   = (const float*)d_in[9];
  const float* n2g    = (const float*)d_in[10];
  const float* n2b    = (const float*)d_in[11];
  const float* w1     = (const float*)d_in[12];
  const float* b1     = (const float*)d_in[13];
  const float* w2     = (const float*)d_in[14];
  const float* b2     = (const float*)d_in[15];
  const float* gw     = (const float*)d_in[16];
  const float* gb     = (const float*)d_in[17];
  const float* dwn    = (const float*)d_in[18];
  const float* dbn    = (const float*)d_in[19];
  const float* uw     = (const float*)d_in[20];
  const float* ub     = (const float*)d_in[21];

  char* ws = (char*)d_ws;
  size_t off = 0;
  auto alloc = [&](size_t bytes){ size_t o = off; off += (bytes + 255) & ~(size_t)255; return o; };

  // shared weights (bf16) — ~11.2 MB
  uint16_t* pqT   = (uint16_t*)(ws + alloc((size_t)1152 * 288 * 2));  // [proj 576 | q 576]
  float*    pqB   = (float*)(ws + alloc((size_t)1152 * 4));
  uint16_t* kvT   = (uint16_t*)(ws + alloc((size_t)1152 * 288 * 2));
  uint16_t* aT    = (uint16_t*)(ws + alloc((size_t)640 * 576 * 2));
  uint16_t* m1T   = (uint16_t*)(ws + alloc((size_t)2304 * 576 * 2));
  uint16_t* m2Te  = (uint16_t*)(ws + alloc((size_t)2 * 640 * 2400 * 2));
  uint16_t* adT   = (uint16_t*)(ws + alloc((size_t)2 * 128 * 576 * 2));
  float*    adB   = (float*)(ws + alloc((size_t)2 * 128 * 4));
  // activations (total ws ~222 MB)
  uint16_t* xn2  = (uint16_t*)(ws + alloc((size_t)65536 * 288 * 2));   // both streams
  uint16_t* sc2  = (uint16_t*)(ws + alloc((size_t)16384 * 576 * 2));   // both streams
  size_t oQP = alloc((size_t)16384 * 576 * 2);       // qp halves; later x2b merged
  uint16_t* qp2  = (uint16_t*)(ws + oQP);
  uint16_t* x2b  = (uint16_t*)(ws + oQP);
  uint16_t* kb   = (uint16_t*)(ws + alloc((size_t)32768 * 576 * 2));   // per-stream reuse
  size_t oVT = alloc((size_t)16384 * 2400 * 2);      // vt (41.9MB, reuse); later mlpA [16384][2400]
  uint16_t* vt   = (uint16_t*)(ws + oVT);
  uint16_t* mlpA = (uint16_t*)(ws + oVT);
  size_t oOB = alloc((size_t)16384 * 576 * 2);       // ob both streams; later hb merged
  uint16_t* ob2  = (uint16_t*)(ws + oOB);
  uint16_t* hb2  = (uint16_t*)(ws + oOB);

  // weight prep (3 launches)
  wprep_k<<<dim3(5184, 6), 256, 0, stream>>>(proj_w, qkv_w, ap_w, w1, proj_b, qkv_b,
                                             pqT, kvT, aT, m1T, pqB);
  mk_m2te_k<<<(2 * 640 * 2400 + 255) / 256, 256, 0, stream>>>(w2, uw, ub, m2Te);
  mk_adt_k<<<(2 * 128 * 576 + 255) / 256, 256, 0, stream>>>(dwn, gw, dbn, gb, adT, adB);

  // LN1 both streams -> xn2 bf16 [65536 x 288]
  ln_k<float><<<16384, 256, 0, stream>>>(rgb, depth, 32768, 288, n1g, n1b, xn2);

  // -------- frontend per stream (kb/vt reused) --------
  for (int si = 0; si < 2; ++si){
    const size_t half = (size_t)si * 8192 * 576;

    // merged pool(proj+q) + kv GEMM (2-buf BM=128 core) -> sc, qp, kb, vt
    gemm_pkv_k<<<dim3(256, 18), 256, 0, stream>>>(xn2 + (size_t)si * 32768 * 288, pqT, kvT,
                                                  pqB, qkv_b + 576,
                                                  sc2 + half, qp2 + half, kb, vt);

    // MFMA windowed attention (2-wave key-split) -> ob bf16
    attn_mfma_k<<<1024, 128, 0, stream>>>(qp2 + half, kb, vt, ob2 + half);
  }

  // -------- backend merged over both streams (M=16384, BM=128) --------
  // attn out-proj + shortcut -> x2b bf16 (aliases qp2, dead after attn)
  gemm_add1_k<<<dim3(128, 5), 256, 0, stream>>>(ob2, aT, ap_b, sc2, x2b);

  // LN2 -> hb bf16 (aliases ob2, dead after add1)
  ln_k<uint16_t><<<4096, 256, 0, stream>>>(x2b, x2b, 16384, 576, n2g, n2b, hb2);

  // MLP up + gelu (cols 0..2303) + adapter phase-1 (cols 2304..2399) -> mlpA (aliases vt)
  gemm_upad_k<<<dim3(128, 19), 256, 0, stream>>>(hb2, x2b, m1T, adT, b1, adB, mlpA);

  // MLP down + adapter up + x2 -> out f32 (K=2400 extended)
  gemm_addf_k<<<dim3(128, 5), 256, 0, stream>>>(mlpA, m2Te, b2, x2b, (float*)d_out);
}